// Round 12
// baseline (591.975 us; speedup 1.0000x reference)
//
#include <hip/hip_runtime.h>
#include <math.h>

#define NC 2000
#define NP 1500
#define NA 40
#define LP 512
#define BSZ 4096
#define NW 8000

typedef _Float16 half8_t __attribute__((ext_vector_type(8)));
typedef _Float16 half4_t __attribute__((ext_vector_type(4)));
typedef float f32x4 __attribute__((ext_vector_type(4)));

// ======================= GNN (fused per compound) =======================
__global__ __launch_bounds__(320) void gnn_kernel(
    const int* __restrict__ compounds, const float* __restrict__ adjacencies,
    const float* __restrict__ embed_fp, const float* __restrict__ W_gnn,
    const float* __restrict__ b_gnn, _Float16* __restrict__ comp_h)
{
    __shared__ float xs[40][68];
    __shared__ float hs[40][68];
    __shared__ float Ws[64][64];
    __shared__ float adjS[40][41];
    __shared__ float bS[64];
    const int n = blockIdx.x;
    const int tid = threadIdx.x;
    const int a = tid >> 3, g = tid & 7, cb = g * 8;

    for (int j = tid; j < 40 * 64; j += 320) {
        int r = j >> 6, c = j & 63;
        xs[r][c] = embed_fp[(size_t)compounds[n * NA + r] * 64 + c];
    }
    for (int j = tid; j < NA * NA; j += 320)
        adjS[j / NA][j % NA] = adjacencies[(size_t)n * (NA * NA) + j];

    for (int l = 0; l < 3; ++l) {
        __syncthreads();
        for (int j = tid; j < 4096; j += 320) Ws[j >> 6][j & 63] = W_gnn[l * 4096 + j];
        if (tid < 64) bS[tid] = b_gnn[l * 64 + tid];
        __syncthreads();
        float acc[8];
        #pragma unroll
        for (int j = 0; j < 8; ++j) acc[j] = bS[cb + j];
        #pragma unroll 8
        for (int d = 0; d < 64; ++d) {
            float x = xs[a][d];
            float4 w0 = *(const float4*)&Ws[d][cb];
            float4 w1 = *(const float4*)&Ws[d][cb + 4];
            acc[0] += x * w0.x; acc[1] += x * w0.y; acc[2] += x * w0.z; acc[3] += x * w0.w;
            acc[4] += x * w1.x; acc[5] += x * w1.y; acc[6] += x * w1.z; acc[7] += x * w1.w;
        }
        #pragma unroll
        for (int j = 0; j < 8; ++j) hs[a][cb + j] = fmaxf(acc[j], 0.f);
        __syncthreads();
        float4 x0 = *(float4*)&xs[a][cb];
        float4 x1 = *(float4*)&xs[a][cb + 4];
        #pragma unroll 8
        for (int b = 0; b < NA; ++b) {
            float ad = adjS[a][b];
            float4 h0 = *(const float4*)&hs[b][cb];
            float4 h1 = *(const float4*)&hs[b][cb + 4];
            x0.x += ad * h0.x; x0.y += ad * h0.y; x0.z += ad * h0.z; x0.w += ad * h0.w;
            x1.x += ad * h1.x; x1.y += ad * h1.y; x1.z += ad * h1.z; x1.w += ad * h1.w;
        }
        *(float4*)&xs[a][cb] = x0;
        *(float4*)&xs[a][cb + 4] = x1;
    }
    __syncthreads();
    if (tid < 64) {
        float s = 0.f;
        for (int r = 0; r < NA; ++r) s += xs[r][tid];
        comp_h[n * 64 + tid] = (_Float16)(s * (1.0f / 40.0f));
    }
}

// ======================= CNN via MFMA (banded 16x16x32 f16) =======================
__device__ __forceinline__ int swz_off(int row, int half_col)
{
    int b = half_col >> 3;
    return row * 128 + (((b & 8) | ((b ^ row) & 7)) << 3) + (half_col & 7);
}

// one-time: wtab (16896 halves) + padded fp16 embed (NW*80)
__global__ void cnn_prep(const float* __restrict__ K_cnn, _Float16* __restrict__ wtab,
                         const float* __restrict__ ew, _Float16* __restrict__ ehp)
{
    int j = blockIdx.x * 256 + threadIdx.x;
    if (j < 16896) {
        int L = j / 5632, rem = j % 5632;
        int dr = rem >> 9, r2 = rem & 511, ln = r2 >> 3, i = r2 & 7;
        int dc = 8 * (ln >> 4) + i - (ln & 15);   // k - n
        float v = (dc >= 0 && dc < 11) ? K_cnn[L * 121 + dr * 11 + dc] : 0.f;
        wtab[j] = (_Float16)v;
        return;
    }
    int e = j - 16896;
    if (e >= NW * 80) return;
    int w = e / 80, h = e - w * 80;
    float v = (h >= 13 && h < 77) ? ew[w * 64 + (h - 13)] : 0.f;
    ehp[e] = (_Float16)v;
}

// one-time: fp16 feature copies + fp16 transposed weights [N][K]
__global__ void prep_h(
    const float* __restrict__ df, const float* __restrict__ pf,
    const float* __restrict__ wd1, const float* __restrict__ wd2, const float* __restrict__ wd3,
    const float* __restrict__ wp1, const float* __restrict__ wp2, const float* __restrict__ wp3,
    const float* __restrict__ wo1, const float* __restrict__ wo2, const float* __restrict__ wo3,
    _Float16* __restrict__ dfh, _Float16* __restrict__ pfh,
    _Float16* __restrict__ wd1t, _Float16* __restrict__ wd2t, _Float16* __restrict__ wd3t,
    _Float16* __restrict__ wp1t, _Float16* __restrict__ wp2t, _Float16* __restrict__ wp3t,
    _Float16* __restrict__ wo1t, _Float16* __restrict__ wo2t, _Float16* __restrict__ wo3t)
{
    int j = blockIdx.x * 256 + threadIdx.x;
    if (j < 2048000) { dfh[j] = (_Float16)df[j]; return; }
    j -= 2048000;
    if (j < 1536000) { pfh[j] = (_Float16)pf[j]; return; }
    j -= 1536000;
    if (j < 131072) { int n = j >> 10, k = j & 1023; wd1t[j] = (_Float16)wd1[k * 128 + n]; return; }
    j -= 131072;
    if (j < 8192)  { int n = j >> 7, k = j & 127; wd2t[j] = (_Float16)wd2[k * 64 + n]; return; }
    j -= 8192;
    if (j < 4096)  { int n = j >> 6, k = j & 63; wd3t[j] = (_Float16)wd3[k * 64 + n]; return; }
    j -= 4096;
    if (j < 131072) { int n = j >> 10, k = j & 1023; wp1t[j] = (_Float16)wp1[k * 128 + n]; return; }
    j -= 131072;
    if (j < 8192)  { int n = j >> 7, k = j & 127; wp2t[j] = (_Float16)wp2[k * 64 + n]; return; }
    j -= 8192;
    if (j < 4096)  { int n = j >> 6, k = j & 63; wp3t[j] = (_Float16)wp3[k * 64 + n]; return; }
    j -= 4096;
    if (j < 98304) { int n = j / 384, k = j - n * 384; wo1t[j] = (_Float16)wo1[k * 256 + n]; return; }
    j -= 98304;
    if (j < 65536) { int n = j >> 8, k = j & 255; wo2t[j] = (_Float16)wo2[k * 256 + n]; return; }
    j -= 65536;
    if (j < 65536) { int n = j >> 8, k = j & 255; wo3t[j] = (_Float16)wo3[k * 256 + n]; return; }
}

__global__ __launch_bounds__(256) void cnn_kernel(
    const int* __restrict__ proteins, const _Float16* __restrict__ ehp,
    const half8_t* __restrict__ wtab, const float* __restrict__ b_cnn,
    float* __restrict__ prot_part)
{
    __shared__ half8_t bufA8[62 * 16];
    __shared__ half8_t bufB8[62 * 16];
    _Float16* bufA = (_Float16*)bufA8;
    _Float16* bufB = (_Float16*)bufB8;

    const int tile = blockIdx.x, p = blockIdx.y;
    const int t0 = tile * 32, tid = threadIdx.x;
    const int lane = tid & 63, wid = tid >> 6;
    const int c0 = wid * 16;
    const int m = lane & 15, g = lane >> 4;

    half8_t z = {};
    for (int e = tid; e < 62 * 9; e += 256) {
        int i = e / 9, a = 1 + (e - 9 * i);
        int gr = t0 - 15 + i;
        half8_t v = z;
        if (gr >= 0 && gr < LP)
            v = *(const half8_t*)&ehp[(size_t)proteins[p * LP + gr] * 80 + 8 * a];
        *(half8_t*)&bufA[i * 128 + (((a & 8) | ((a ^ i) & 7)) << 3)] = v;
    }
    // zero read-but-never-stored blocks: bufA blk10; bufB blk1, blk9, blk10
    for (int e = tid; e < 62 * 4; e += 256) {
        int i = e >> 2, w = e & 3;
        if (w == 0)      bufA8[i * 16 + (8 | ((10 ^ i) & 7))] = z;
        else if (w == 1) bufB8[i * 16 + ((1 ^ i) & 7)] = z;
        else {
            int blk = 7 + w;
            bufB8[i * 16 + ((blk & 8) | ((blk ^ i) & 7))] = z;
        }
    }

    half8_t wf[11];
    auto load_wf = [&](int L) {
        #pragma unroll
        for (int dr = 0; dr < 11; ++dr) wf[dr] = wtab[L * 11 * 64 + dr * 64 + lane];
    };
    auto conv_tile = [&](const _Float16* src, int r0, float bias) -> f32x4 {
        f32x4 acc = {bias, bias, bias, bias};
        const int B0 = (c0 + 8) >> 3;
        #pragma unroll
        for (int dr = 0; dr < 11; ++dr) {
            int R = r0 - 5 + dr + m;
            int b = B0 + g;
            half8_t a = *(const half8_t*)&src[R * 128 + (((b & 8) | ((b ^ R) & 7)) << 3)];
            acc = __builtin_amdgcn_mfma_f32_16x16x32_f16(a, wf[dr], acc, 0, 0, 0);
        }
        return acc;
    };
    auto store_tile = [&](_Float16* dst, int r0, f32x4 acc) {
        int pc = c0 + 13 + m;
        #pragma unroll
        for (int j = 0; j < 4; ++j) {
            int row = r0 + 4 * g + j;
            int og = t0 - 15 + row;
            float v = fmaxf(acc[j], 0.f);
            dst[swz_off(row, pc)] = (_Float16)((og >= 0 && og < LP) ? v : 0.f);
        }
    };

    load_wf(0);
    __syncthreads();
    {
        float b0 = b_cnn[0];
        const int r0s[4] = {5, 21, 37, 41};
        #pragma unroll
        for (int k = 0; k < 4; ++k) store_tile(bufB, r0s[k], conv_tile(bufA, r0s[k], b0));
    }
    __syncthreads();
    load_wf(1);
    {
        float b1 = b_cnn[1];
        const int r0s[3] = {10, 26, 36};
        #pragma unroll
        for (int k = 0; k < 3; ++k) store_tile(bufA, r0s[k], conv_tile(bufB, r0s[k], b1));
    }
    __syncthreads();
    load_wf(2);
    {
        float b2 = b_cnn[2];
        float cs = 0.f;
        const int r0s[2] = {15, 31};
        #pragma unroll
        for (int k = 0; k < 2; ++k) {
            f32x4 acc = conv_tile(bufA, r0s[k], b2);
            #pragma unroll
            for (int j = 0; j < 4; ++j) cs += fmaxf(acc[j], 0.f);
        }
        cs += __shfl_xor(cs, 16, 64);
        cs += __shfl_xor(cs, 32, 64);
        if (lane < 16)
            prot_part[((size_t)p * 16 + tile) * 64 + c0 + lane] = cs;
    }
}

__global__ void cnn_reduce(const float* __restrict__ prot_part, _Float16* __restrict__ prot_h)
{
    const int p = blockIdx.x, c = threadIdx.x;
    float s = 0.f;
    for (int t = 0; t < 16; ++t) s += prot_part[((size_t)p * 16 + t) * 64 + c];
    prot_h[p * 64 + c] = (_Float16)(s * (1.0f / 512.0f));
}

// ======== GCN: dual split-K GEMM (drug z=0, protein z=1) + dual epilogue ========
__global__ __launch_bounds__(256) void spk_gemm64_dual(
    const float* __restrict__ A0, const float* __restrict__ X0, float* __restrict__ P0, int M0, int kc0,
    const float* __restrict__ A1, const float* __restrict__ X1, float* __restrict__ P1, int M1, int kc1, int nx1)
{
    const float* A; const float* X; float* part; int M, kchunk;
    if (blockIdx.z == 0) { A = A0; X = X0; part = P0; M = M0; kchunk = kc0; }
    else { if ((int)blockIdx.x >= nx1) return; A = A1; X = X1; part = P1; M = M1; kchunk = kc1; }

    __shared__ float As[64][17];
    __shared__ float Xs[16][64];
    const int rb = blockIdx.x * 64;
    const int s = blockIdx.y;
    const int k0 = s * kchunk;
    const int k1 = (k0 + kchunk < M) ? (k0 + kchunk) : M;
    const int tid = threadIdx.x, tx = tid & 15, ty = tid >> 4;
    float acc[4][4] = {};
    for (int kb = k0; kb < k1; kb += 16) {
        #pragma unroll
        for (int q = 0; q < 4; ++q) {
            int r = (tid >> 4) + q * 16, kc = tid & 15;
            int row = rb + r, kidx = kb + kc;
            As[r][kc] = (row < M && kidx < k1) ? A[(size_t)row * M + kidx] : 0.f;
        }
        #pragma unroll
        for (int q = 0; q < 4; ++q) {
            int kr = (tid >> 6) + q * 4, cc = tid & 63;
            int kidx = kb + kr;
            Xs[kr][cc] = (kidx < k1) ? X[(size_t)kidx * 64 + cc] : 0.f;
        }
        __syncthreads();
        #pragma unroll
        for (int kk = 0; kk < 16; ++kk) {
            float a0 = As[ty * 4 + 0][kk], a1 = As[ty * 4 + 1][kk];
            float a2 = As[ty * 4 + 2][kk], a3 = As[ty * 4 + 3][kk];
            float4 b4 = *(const float4*)&Xs[kk][tx * 4];
            acc[0][0] += a0 * b4.x; acc[0][1] += a0 * b4.y; acc[0][2] += a0 * b4.z; acc[0][3] += a0 * b4.w;
            acc[1][0] += a1 * b4.x; acc[1][1] += a1 * b4.y; acc[1][2] += a1 * b4.z; acc[1][3] += a1 * b4.w;
            acc[2][0] += a2 * b4.x; acc[2][1] += a2 * b4.y; acc[2][2] += a2 * b4.z; acc[2][3] += a2 * b4.w;
            acc[3][0] += a3 * b4.x; acc[3][1] += a3 * b4.y; acc[3][2] += a3 * b4.z; acc[3][3] += a3 * b4.w;
        }
        __syncthreads();
    }
    #pragma unroll
    for (int i = 0; i < 4; ++i) {
        int row = rb + ty * 4 + i;
        if (row < M)
            *(float4*)&part[((size_t)s * M + row) * 64 + tx * 4] =
                make_float4(acc[i][0], acc[i][1], acc[i][2], acc[i][3]);
    }
}

__global__ __launch_bounds__(256) void gcn_epi_dual(
    const float* __restrict__ P0, int M0, const float* __restrict__ W0, const float* __restrict__ b0,
    float* __restrict__ O0, _Float16* __restrict__ H0,
    const float* __restrict__ P1, int M1, const float* __restrict__ W1, const float* __restrict__ b1,
    float* __restrict__ O1, _Float16* __restrict__ H1, int nx1)
{
    const float* part; const float* W; const float* bias; float* Xout; _Float16* H; int M;
    if (blockIdx.z == 0) { part = P0; W = W0; bias = b0; Xout = O0; H = H0; M = M0; }
    else { if ((int)blockIdx.x >= nx1) return; part = P1; W = W1; bias = b1; Xout = O1; H = H1; M = M1; }

    __shared__ float Ys[64][68];
    __shared__ float Ws[64][64];
    const int rb = blockIdx.x * 64;
    const int tid = threadIdx.x;
    for (int j = tid; j < 4096; j += 256) Ws[j >> 6][j & 63] = W[j];
    for (int j = tid; j < 4096; j += 256) {
        int r = j >> 6, c = j & 63;
        float sum = 0.f;
        if (rb + r < M)
            for (int t = 0; t < 8; ++t) sum += part[((size_t)t * M + rb + r) * 64 + c];
        Ys[r][c] = sum;
    }
    __syncthreads();
    const int tx = tid & 15, ty = tid >> 4;
    float acc[4][4];
    #pragma unroll
    for (int i = 0; i < 4; ++i)
        #pragma unroll
        for (int j = 0; j < 4; ++j) acc[i][j] = bias[tx * 4 + j];
    for (int d = 0; d < 64; ++d) {
        float a0 = Ys[ty * 4 + 0][d], a1 = Ys[ty * 4 + 1][d];
        float a2 = Ys[ty * 4 + 2][d], a3 = Ys[ty * 4 + 3][d];
        float4 w4 = *(const float4*)&Ws[d][tx * 4];
        acc[0][0] += a0 * w4.x; acc[0][1] += a0 * w4.y; acc[0][2] += a0 * w4.z; acc[0][3] += a0 * w4.w;
        acc[1][0] += a1 * w4.x; acc[1][1] += a1 * w4.y; acc[1][2] += a1 * w4.z; acc[1][3] += a1 * w4.w;
        acc[2][0] += a2 * w4.x; acc[2][1] += a2 * w4.y; acc[2][2] += a2 * w4.z; acc[2][3] += a2 * w4.w;
        acc[3][0] += a3 * w4.x; acc[3][1] += a3 * w4.y; acc[3][2] += a3 * w4.z; acc[3][3] += a3 * w4.w;
    }
    #pragma unroll
    for (int i = 0; i < 4; ++i) {
        int row = rb + ty * 4 + i;
        if (row < M) {
            #pragma unroll
            for (int j = 0; j < 4; ++j) {
                float v = fmaxf(acc[i][j], 0.f);
                if (Xout) Xout[(size_t)row * 64 + tx * 4 + j] = v;
                if (H)    H[(size_t)row * 64 + tx * 4 + j] = (_Float16)v;
            }
        }
    }
}

// ======== MFMA MLP GEMM: C=relu(A@B+bias), A fp16 [M][K] (opt row-gather),
// Bt fp16 [N][K], C fp16 [M][N]. No LDS staging; per-wave 16 rows x N cols. ====
template<int NT, bool GATHER>
__global__ __launch_bounds__(256) void mfma_mlp(
    const _Float16* __restrict__ A0, const int* __restrict__ idx0,
    const _Float16* __restrict__ Bt0, const float* __restrict__ bias0, _Float16* __restrict__ C0,
    const _Float16* __restrict__ A1, const int* __restrict__ idx1,
    const _Float16* __restrict__ Bt1, const float* __restrict__ bias1, _Float16* __restrict__ C1,
    int K)
{
    const _Float16* A; const int* idx; const _Float16* Bt; const float* bias; _Float16* C;
    if (blockIdx.z == 0) { A = A0; idx = idx0; Bt = Bt0; bias = bias0; C = C0; }
    else                 { A = A1; idx = idx1; Bt = Bt1; bias = bias1; C = C1; }
    constexpr int N = NT * 16;
    const int tid = threadIdx.x, wid = tid >> 6, lane = tid & 63;
    const int m = lane & 15, g = lane >> 4;
    const int row0 = blockIdx.x * 64 + wid * 16;
    size_t arow = GATHER ? (size_t)idx[row0 + m] : (size_t)(row0 + m);
    const _Float16* Ap = A + arow * (size_t)K + 8 * g;
    f32x4 acc[NT] = {};
    for (int kb = 0; kb < K; kb += 32) {
        half8_t af = *(const half8_t*)&Ap[kb];
        #pragma unroll
        for (int t = 0; t < NT; ++t) {
            half8_t bf = *(const half8_t*)&Bt[(size_t)(t * 16 + m) * K + kb + 8 * g];
            acc[t] = __builtin_amdgcn_mfma_f32_16x16x32_f16(af, bf, acc[t], 0, 0, 0);
        }
    }
    __shared__ float cb[4][16][17];
    const int rr = lane >> 2, c4 = (lane & 3) * 4;
    #pragma unroll
    for (int t = 0; t < NT; ++t) {
        #pragma unroll
        for (int j = 0; j < 4; ++j) cb[wid][4 * g + j][m] = acc[t][j];
        half4_t h;
        #pragma unroll
        for (int j = 0; j < 4; ++j)
            h[j] = (_Float16)fmaxf(cb[wid][rr][c4 + j] + bias[t * 16 + c4 + j], 0.f);
        *(half4_t*)&C[(size_t)(row0 + rr) * N + t * 16 + c4] = h;
    }
}

// head GEMM1 with fused concat: K=384 over 6 fp16 [.][64] sources, N=256
__global__ __launch_bounds__(256) void mfma_head1(
    const int* __restrict__ idx_c, const int* __restrict__ idx_p,
    const _Float16* __restrict__ ci, const _Float16* __restrict__ xc, const _Float16* __restrict__ fd,
    const _Float16* __restrict__ pi, const _Float16* __restrict__ xp, const _Float16* __restrict__ fp,
    const _Float16* __restrict__ Bt, const float* __restrict__ bias, _Float16* __restrict__ C)
{
    const int tid = threadIdx.x, wid = tid >> 6, lane = tid & 63;
    const int m = lane & 15, g = lane >> 4;
    const int row0 = blockIdx.x * 64 + wid * 16;
    int ic = idx_c[row0 + m], ip = idx_p[row0 + m];
    const _Float16* segs[6] = {
        ci + (size_t)ic * 64 + 8 * g,  xc + (size_t)ic * 64 + 8 * g,
        fd + (size_t)(row0 + m) * 64 + 8 * g,
        pi + (size_t)ip * 64 + 8 * g,  xp + (size_t)ip * 64 + 8 * g,
        fp + (size_t)(row0 + m) * 64 + 8 * g };
    f32x4 acc[16] = {};
    #pragma unroll
    for (int kb = 0; kb < 384; kb += 32) {
        half8_t af = *(const half8_t*)&segs[kb / 64][kb & 63];   // kb static after unroll
        #pragma unroll
        for (int t = 0; t < 16; ++t) {
            half8_t bf = *(const half8_t*)&Bt[(size_t)(t * 16 + m) * 384 + kb + 8 * g];
            acc[t] = __builtin_amdgcn_mfma_f32_16x16x32_f16(af, bf, acc[t], 0, 0, 0);
        }
    }
    __shared__ float cb[4][16][17];
    const int rr = lane >> 2, c4 = (lane & 3) * 4;
    #pragma unroll
    for (int t = 0; t < 16; ++t) {
        #pragma unroll
        for (int j = 0; j < 4; ++j) cb[wid][4 * g + j][m] = acc[t][j];
        half4_t h;
        #pragma unroll
        for (int j = 0; j < 4; ++j)
            h[j] = (_Float16)fmaxf(cb[wid][rr][c4 + j] + bias[t * 16 + c4 + j], 0.f);
        *(half4_t*)&C[(size_t)(row0 + rr) * 256 + t * 16 + c4] = h;
    }
}

// head GEMM3 (K=256,N=256) with fused final 256x2 matmul + sigmoid
__global__ __launch_bounds__(256) void mfma_head3(
    const _Float16* __restrict__ A, const _Float16* __restrict__ Bt,
    const float* __restrict__ bias, const float* __restrict__ Wi, const float* __restrict__ bi,
    float* __restrict__ out)
{
    const int tid = threadIdx.x, wid = tid >> 6, lane = tid & 63;
    const int m = lane & 15, g = lane >> 4;
    const int row0 = blockIdx.x * 64 + wid * 16;
    const _Float16* Ap = A + (size_t)(row0 + m) * 256 + 8 * g;
    f32x4 acc[16] = {};
    for (int kb = 0; kb < 256; kb += 32) {
        half8_t af = *(const half8_t*)&Ap[kb];
        #pragma unroll
        for (int t = 0; t < 16; ++t) {
            half8_t bf = *(const half8_t*)&Bt[(size_t)(t * 16 + m) * 256 + kb + 8 * g];
            acc[t] = __builtin_amdgcn_mfma_f32_16x16x32_f16(af, bf, acc[t], 0, 0, 0);
        }
    }
    float p0[4] = {}, p1[4] = {};
    #pragma unroll
    for (int t = 0; t < 16; ++t) {
        float w0 = Wi[(t * 16 + m) * 2], w1 = Wi[(t * 16 + m) * 2 + 1];
        float bc = bias[t * 16 + m];
        #pragma unroll
        for (int j = 0; j < 4; ++j) {
            float v = fmaxf(acc[t][j] + bc, 0.f);
            p0[j] += v * w0; p1[j] += v * w1;
        }
    }
    #pragma unroll
    for (int d = 1; d < 16; d <<= 1) {
        #pragma unroll
        for (int j = 0; j < 4; ++j) {
            p0[j] += __shfl_xor(p0[j], d, 64);
            p1[j] += __shfl_xor(p1[j], d, 64);
        }
    }
    if (m == 0) {
        float B0 = bi[0], B1 = bi[1];
        #pragma unroll
        for (int j = 0; j < 4; ++j) {
            int r = row0 + 4 * g + j;
            out[r * 2 + 0] = 1.f / (1.f + expf(-(p0[j] + B0)));
            out[r * 2 + 1] = 1.f / (1.f + expf(-(p1[j] + B1)));
        }
    }
}

// ======================= launch =======================
extern "C" void kernel_launch(void* const* d_in, const int* in_sizes, int n_in,
                              void* d_out, int out_size, void* d_ws, size_t ws_size,
                              hipStream_t stream)
{
    const int*   idx_c        = (const int*)  d_in[0];
    const int*   idx_p        = (const int*)  d_in[1];
    const int*   compounds    = (const int*)  d_in[2];
    const int*   proteins     = (const int*)  d_in[3];
    const float* adjacencies  = (const float*)d_in[4];
    const float* A_c          = (const float*)d_in[5];
    const float* A_p          = (const float*)d_in[6];
    const float* embed_fp     = (const float*)d_in[7];
    const float* embed_word   = (const float*)d_in[8];
    const float* Xs_c         = (const float*)d_in[9];
    const float* Xs_p         = (const float*)d_in[10];
    const float* drug_feat    = (const float*)d_in[11];
    const float* protein_feat = (const float*)d_in[12];
    const float* W_gnn        = (const float*)d_in[13];
    const float* b_gnn        = (const float*)d_in[14];
    const float* K_cnn        = (const float*)d_in[15];
    const float* b_cnn        = (const float*)d_in[16];
    const float* W_gcn_d      = (const float*)d_in[17];
    const float* b_gcn_d      = (const float*)d_in[18];
    const float* W_gcn_p      = (const float*)d_in[19];
    const float* b_gcn_p      = (const float*)d_in[20];
    const float* Wd1 = (const float*)d_in[21]; const float* bd1 = (const float*)d_in[22];
    const float* Wd2 = (const float*)d_in[23]; const float* bd2 = (const float*)d_in[24];
    const float* Wd3 = (const float*)d_in[25]; const float* bd3 = (const float*)d_in[26];
    const float* Wp1 = (const float*)d_in[27]; const float* bp1 = (const float*)d_in[28];
    const float* Wp2 = (const float*)d_in[29]; const float* bp2 = (const float*)d_in[30];
    const float* Wp3 = (const float*)d_in[31]; const float* bp3 = (const float*)d_in[32];
    const float* Wo1 = (const float*)d_in[33]; const float* bo1 = (const float*)d_in[34];
    const float* Wo2 = (const float*)d_in[35]; const float* bo2 = (const float*)d_in[36];
    const float* Wo3 = (const float*)d_in[37]; const float* bo3 = (const float*)d_in[38];
    const float* W_int = (const float*)d_in[39]; const float* b_int = (const float*)d_in[40];

    float* ws = (float*)d_ws;
    float* prot_part = ws; ws += NP * 16 * 64;
    float* wtab_g    = ws; ws += 8448;
    float* ehp_g     = ws; ws += NW * 40;
    float* part_c    = ws; ws += 8 * NC * 64;
    float* part_p    = ws; ws += 8 * NP * 64;
    float* Xc_a = ws; ws += NC * 64;
    float* Xp_a = ws; ws += NP * 64;
    // fp16 buffers (sizes in float units = halves/2)
    _Float16* comp_h  = (_Float16*)ws; ws += NC * 32;
    _Float16* prot_h  = (_Float16*)ws; ws += NP * 32;
    _Float16* Xcb_h   = (_Float16*)ws; ws += NC * 32;
    _Float16* Xpb_h   = (_Float16*)ws; ws += NP * 32;
    _Float16* drug_h  = (_Float16*)ws; ws += NC * 512;
    _Float16* protf_h = (_Float16*)ws; ws += NP * 512;
    _Float16* wd1t = (_Float16*)ws; ws += 65536;
    _Float16* wd2t = (_Float16*)ws; ws += 4096;
    _Float16* wd3t = (_Float16*)ws; ws += 2048;
    _Float16* wp1t = (_Float16*)ws; ws += 65536;
    _Float16* wp2t = (_Float16*)ws; ws += 4096;
    _Float16* wp3t = (_Float16*)ws; ws += 2048;
    _Float16* wo1t = (_Float16*)ws; ws += 49152;
    _Float16* wo2t = (_Float16*)ws; ws += 32768;
    _Float16* wo3t = (_Float16*)ws; ws += 32768;
    _Float16* fd1h = (_Float16*)ws; ws += BSZ * 64;
    _Float16* fd2h = (_Float16*)ws; ws += BSZ * 32;
    _Float16* fd3h = (_Float16*)ws; ws += BSZ * 32;
    _Float16* fp1h = (_Float16*)ws; ws += BSZ * 64;
    _Float16* fp2h = (_Float16*)ws; ws += BSZ * 32;
    _Float16* fp3h = (_Float16*)ws; ws += BSZ * 32;
    _Float16* h1h  = (_Float16*)ws; ws += BSZ * 128;
    _Float16* h2h  = (_Float16*)ws; ws += BSZ * 128;
    (void)ws_size; (void)in_sizes; (void)n_in; (void)out_size;

    // one-time prep
    cnn_prep<<<(16896 + NW * 80 + 255) / 256, 256, 0, stream>>>(
        K_cnn, (_Float16*)wtab_g, embed_word, (_Float16*)ehp_g);
    prep_h<<<(4100096 + 255) / 256, 256, 0, stream>>>(
        drug_feat, protein_feat, Wd1, Wd2, Wd3, Wp1, Wp2, Wp3, Wo1, Wo2, Wo3,
        drug_h, protf_h, wd1t, wd2t, wd3t, wp1t, wp2t, wp3t, wo1t, wo2t, wo3t);
    // branch 1: compound GNN
    gnn_kernel<<<NC, 320, 0, stream>>>(compounds, adjacencies, embed_fp, W_gnn, b_gnn, comp_h);
    // branch 2: protein CNN
    cnn_kernel<<<dim3(16, NP), 256, 0, stream>>>(proteins, (const _Float16*)ehp_g,
                                                 (const half8_t*)wtab_g, b_cnn, prot_part);
    cnn_reduce<<<NP, 64, 0, stream>>>(prot_part, prot_h);
    // branch 3: GCN drug+protein
    spk_gemm64_dual<<<dim3(32, 8, 2), 256, 0, stream>>>(
        A_c, Xs_c, part_c, NC, 256, A_p, Xs_p, part_p, NP, 192, 24);
    gcn_epi_dual<<<dim3(32, 1, 2), 256, 0, stream>>>(
        part_c, NC, W_gcn_d, b_gcn_d, Xc_a, nullptr,
        part_p, NP, W_gcn_p, b_gcn_p, Xp_a, nullptr, 24);
    spk_gemm64_dual<<<dim3(32, 8, 2), 256, 0, stream>>>(
        A_c, Xc_a, part_c, NC, 256, A_p, Xp_a, part_p, NP, 192, 24);
    gcn_epi_dual<<<dim3(32, 1, 2), 256, 0, stream>>>(
        part_c, NC, W_gcn_d + 4096, b_gcn_d + 64, nullptr, Xcb_h,
        part_p, NP, W_gcn_p + 4096, b_gcn_p + 64, nullptr, Xpb_h, 24);
    // branches 4+5: annotation MLPs (MFMA, dual)
    mfma_mlp<8, true ><<<dim3(64, 1, 2), 256, 0, stream>>>(
        drug_h, idx_c, wd1t, bd1, fd1h, protf_h, idx_p, wp1t, bp1, fp1h, 1024);
    mfma_mlp<4, false><<<dim3(64, 1, 2), 256, 0, stream>>>(
        fd1h, nullptr, wd2t, bd2, fd2h, fp1h, nullptr, wp2t, bp2, fp2h, 128);
    mfma_mlp<4, false><<<dim3(64, 1, 2), 256, 0, stream>>>(
        fd2h, nullptr, wd3t, bd3, fd3h, fp2h, nullptr, wp3t, bp3, fp3h, 64);
    // head (MFMA): concat-fused GEMM1, GEMM2, GEMM3+final
    mfma_head1<<<64, 256, 0, stream>>>(idx_c, idx_p, comp_h, Xcb_h, fd3h,
                                       prot_h, Xpb_h, fp3h, wo1t, bo1, h1h);
    mfma_mlp<16, false><<<dim3(64, 1, 1), 256, 0, stream>>>(
        h1h, nullptr, wo2t, bo2, h2h, h1h, nullptr, wo2t, bo2, h2h, 256);
    mfma_head3<<<64, 256, 0, stream>>>(h2h, wo3t, bo3, W_int, b_int, (float*)d_out);
}

// Round 13
// 491.470 us; speedup vs baseline: 1.2045x; 1.2045x over previous
//
#include <hip/hip_runtime.h>
#include <math.h>

#define NC 2000
#define NP 1500
#define NA 40
#define LP 512
#define BSZ 4096
#define NW 8000

typedef _Float16 half8_t __attribute__((ext_vector_type(8)));
typedef _Float16 half4_t __attribute__((ext_vector_type(4)));
typedef float f32x4 __attribute__((ext_vector_type(4)));

// ======================= GNN (fused per compound) =======================
__global__ __launch_bounds__(320) void gnn_kernel(
    const int* __restrict__ compounds, const float* __restrict__ adjacencies,
    const float* __restrict__ embed_fp, const float* __restrict__ W_gnn,
    const float* __restrict__ b_gnn, _Float16* __restrict__ comp_h)
{
    __shared__ float xs[40][68];
    __shared__ float hs[40][68];
    __shared__ float Ws[64][64];
    __shared__ float adjS[40][41];
    __shared__ float bS[64];
    const int n = blockIdx.x;
    const int tid = threadIdx.x;
    const int a = tid >> 3, g = tid & 7, cb = g * 8;

    for (int j = tid; j < 40 * 64; j += 320) {
        int r = j >> 6, c = j & 63;
        xs[r][c] = embed_fp[(size_t)compounds[n * NA + r] * 64 + c];
    }
    for (int j = tid; j < NA * NA; j += 320)
        adjS[j / NA][j % NA] = adjacencies[(size_t)n * (NA * NA) + j];

    for (int l = 0; l < 3; ++l) {
        __syncthreads();
        for (int j = tid; j < 4096; j += 320) Ws[j >> 6][j & 63] = W_gnn[l * 4096 + j];
        if (tid < 64) bS[tid] = b_gnn[l * 64 + tid];
        __syncthreads();
        float acc[8];
        #pragma unroll
        for (int j = 0; j < 8; ++j) acc[j] = bS[cb + j];
        #pragma unroll 8
        for (int d = 0; d < 64; ++d) {
            float x = xs[a][d];
            float4 w0 = *(const float4*)&Ws[d][cb];
            float4 w1 = *(const float4*)&Ws[d][cb + 4];
            acc[0] += x * w0.x; acc[1] += x * w0.y; acc[2] += x * w0.z; acc[3] += x * w0.w;
            acc[4] += x * w1.x; acc[5] += x * w1.y; acc[6] += x * w1.z; acc[7] += x * w1.w;
        }
        #pragma unroll
        for (int j = 0; j < 8; ++j) hs[a][cb + j] = fmaxf(acc[j], 0.f);
        __syncthreads();
        float4 x0 = *(float4*)&xs[a][cb];
        float4 x1 = *(float4*)&xs[a][cb + 4];
        #pragma unroll 8
        for (int b = 0; b < NA; ++b) {
            float ad = adjS[a][b];
            float4 h0 = *(const float4*)&hs[b][cb];
            float4 h1 = *(const float4*)&hs[b][cb + 4];
            x0.x += ad * h0.x; x0.y += ad * h0.y; x0.z += ad * h0.z; x0.w += ad * h0.w;
            x1.x += ad * h1.x; x1.y += ad * h1.y; x1.z += ad * h1.z; x1.w += ad * h1.w;
        }
        *(float4*)&xs[a][cb] = x0;
        *(float4*)&xs[a][cb + 4] = x1;
    }
    __syncthreads();
    if (tid < 64) {
        float s = 0.f;
        for (int r = 0; r < NA; ++r) s += xs[r][tid];
        comp_h[n * 64 + tid] = (_Float16)(s * (1.0f / 40.0f));
    }
}

// ======================= CNN via MFMA (banded 16x16x32 f16) =======================
__device__ __forceinline__ int swz_off(int row, int half_col)
{
    int b = half_col >> 3;
    return row * 128 + (((b & 8) | ((b ^ row) & 7)) << 3) + (half_col & 7);
}

// one-time: wtab (16896 halves) + padded fp16 embed (NW*80)
__global__ void cnn_prep(const float* __restrict__ K_cnn, _Float16* __restrict__ wtab,
                         const float* __restrict__ ew, _Float16* __restrict__ ehp)
{
    int j = blockIdx.x * 256 + threadIdx.x;
    if (j < 16896) {
        int L = j / 5632, rem = j % 5632;
        int dr = rem >> 9, r2 = rem & 511, ln = r2 >> 3, i = r2 & 7;
        int dc = 8 * (ln >> 4) + i - (ln & 15);   // k - n
        float v = (dc >= 0 && dc < 11) ? K_cnn[L * 121 + dr * 11 + dc] : 0.f;
        wtab[j] = (_Float16)v;
        return;
    }
    int e = j - 16896;
    if (e >= NW * 80) return;
    int w = e / 80, h = e - w * 80;
    float v = (h >= 13 && h < 77) ? ew[w * 64 + (h - 13)] : 0.f;
    ehp[e] = (_Float16)v;
}

// one-time: fp16 feature copies + fp16 transposed weights [N][K]
__global__ void prep_h(
    const float* __restrict__ df, const float* __restrict__ pf,
    const float* __restrict__ wd1, const float* __restrict__ wd2, const float* __restrict__ wd3,
    const float* __restrict__ wp1, const float* __restrict__ wp2, const float* __restrict__ wp3,
    const float* __restrict__ wo1, const float* __restrict__ wo2, const float* __restrict__ wo3,
    _Float16* __restrict__ dfh, _Float16* __restrict__ pfh,
    _Float16* __restrict__ wd1t, _Float16* __restrict__ wd2t, _Float16* __restrict__ wd3t,
    _Float16* __restrict__ wp1t, _Float16* __restrict__ wp2t, _Float16* __restrict__ wp3t,
    _Float16* __restrict__ wo1t, _Float16* __restrict__ wo2t, _Float16* __restrict__ wo3t)
{
    int j = blockIdx.x * 256 + threadIdx.x;
    if (j < 2048000) { dfh[j] = (_Float16)df[j]; return; }
    j -= 2048000;
    if (j < 1536000) { pfh[j] = (_Float16)pf[j]; return; }
    j -= 1536000;
    if (j < 131072) { int n = j >> 10, k = j & 1023; wd1t[j] = (_Float16)wd1[k * 128 + n]; return; }
    j -= 131072;
    if (j < 8192)  { int n = j >> 7, k = j & 127; wd2t[j] = (_Float16)wd2[k * 64 + n]; return; }
    j -= 8192;
    if (j < 4096)  { int n = j >> 6, k = j & 63; wd3t[j] = (_Float16)wd3[k * 64 + n]; return; }
    j -= 4096;
    if (j < 131072) { int n = j >> 10, k = j & 1023; wp1t[j] = (_Float16)wp1[k * 128 + n]; return; }
    j -= 131072;
    if (j < 8192)  { int n = j >> 7, k = j & 127; wp2t[j] = (_Float16)wp2[k * 64 + n]; return; }
    j -= 8192;
    if (j < 4096)  { int n = j >> 6, k = j & 63; wp3t[j] = (_Float16)wp3[k * 64 + n]; return; }
    j -= 4096;
    if (j < 98304) { int n = j / 384, k = j - n * 384; wo1t[j] = (_Float16)wo1[k * 256 + n]; return; }
    j -= 98304;
    if (j < 65536) { int n = j >> 8, k = j & 255; wo2t[j] = (_Float16)wo2[k * 256 + n]; return; }
    j -= 65536;
    if (j < 65536) { int n = j >> 8, k = j & 255; wo3t[j] = (_Float16)wo3[k * 256 + n]; return; }
}

__global__ __launch_bounds__(256) void cnn_kernel(
    const int* __restrict__ proteins, const _Float16* __restrict__ ehp,
    const half8_t* __restrict__ wtab, const float* __restrict__ b_cnn,
    float* __restrict__ prot_part)
{
    __shared__ half8_t bufA8[62 * 16];
    __shared__ half8_t bufB8[62 * 16];
    _Float16* bufA = (_Float16*)bufA8;
    _Float16* bufB = (_Float16*)bufB8;

    const int tile = blockIdx.x, p = blockIdx.y;
    const int t0 = tile * 32, tid = threadIdx.x;
    const int lane = tid & 63, wid = tid >> 6;
    const int c0 = wid * 16;
    const int m = lane & 15, g = lane >> 4;

    half8_t z = {};
    for (int e = tid; e < 62 * 9; e += 256) {
        int i = e / 9, a = 1 + (e - 9 * i);
        int gr = t0 - 15 + i;
        half8_t v = z;
        if (gr >= 0 && gr < LP)
            v = *(const half8_t*)&ehp[(size_t)proteins[p * LP + gr] * 80 + 8 * a];
        *(half8_t*)&bufA[i * 128 + (((a & 8) | ((a ^ i) & 7)) << 3)] = v;
    }
    // zero read-but-never-stored blocks: bufA blk10; bufB blk1, blk9, blk10
    for (int e = tid; e < 62 * 4; e += 256) {
        int i = e >> 2, w = e & 3;
        if (w == 0)      bufA8[i * 16 + (8 | ((10 ^ i) & 7))] = z;
        else if (w == 1) bufB8[i * 16 + ((1 ^ i) & 7)] = z;
        else {
            int blk = 7 + w;
            bufB8[i * 16 + ((blk & 8) | ((blk ^ i) & 7))] = z;
        }
    }

    half8_t wf[11];
    auto load_wf = [&](int L) {
        #pragma unroll
        for (int dr = 0; dr < 11; ++dr) wf[dr] = wtab[L * 11 * 64 + dr * 64 + lane];
    };
    auto conv_tile = [&](const _Float16* src, int r0, float bias) -> f32x4 {
        f32x4 acc = {bias, bias, bias, bias};
        const int B0 = (c0 + 8) >> 3;
        #pragma unroll
        for (int dr = 0; dr < 11; ++dr) {
            int R = r0 - 5 + dr + m;
            int b = B0 + g;
            half8_t a = *(const half8_t*)&src[R * 128 + (((b & 8) | ((b ^ R) & 7)) << 3)];
            acc = __builtin_amdgcn_mfma_f32_16x16x32_f16(a, wf[dr], acc, 0, 0, 0);
        }
        return acc;
    };
    auto store_tile = [&](_Float16* dst, int r0, f32x4 acc) {
        int pc = c0 + 13 + m;
        #pragma unroll
        for (int j = 0; j < 4; ++j) {
            int row = r0 + 4 * g + j;
            int og = t0 - 15 + row;
            float v = fmaxf(acc[j], 0.f);
            dst[swz_off(row, pc)] = (_Float16)((og >= 0 && og < LP) ? v : 0.f);
        }
    };

    load_wf(0);
    __syncthreads();
    {
        float b0 = b_cnn[0];
        const int r0s[4] = {5, 21, 37, 41};
        #pragma unroll
        for (int k = 0; k < 4; ++k) store_tile(bufB, r0s[k], conv_tile(bufA, r0s[k], b0));
    }
    __syncthreads();
    load_wf(1);
    {
        float b1 = b_cnn[1];
        const int r0s[3] = {10, 26, 36};
        #pragma unroll
        for (int k = 0; k < 3; ++k) store_tile(bufA, r0s[k], conv_tile(bufB, r0s[k], b1));
    }
    __syncthreads();
    load_wf(2);
    {
        float b2 = b_cnn[2];
        float cs = 0.f;
        const int r0s[2] = {15, 31};
        #pragma unroll
        for (int k = 0; k < 2; ++k) {
            f32x4 acc = conv_tile(bufA, r0s[k], b2);
            #pragma unroll
            for (int j = 0; j < 4; ++j) cs += fmaxf(acc[j], 0.f);
        }
        cs += __shfl_xor(cs, 16, 64);
        cs += __shfl_xor(cs, 32, 64);
        if (lane < 16)
            prot_part[((size_t)p * 16 + tile) * 64 + c0 + lane] = cs;
    }
}

__global__ void cnn_reduce(const float* __restrict__ prot_part, _Float16* __restrict__ prot_h)
{
    const int p = blockIdx.x, c = threadIdx.x;
    float s = 0.f;
    for (int t = 0; t < 16; ++t) s += prot_part[((size_t)p * 16 + t) * 64 + c];
    prot_h[p * 64 + c] = (_Float16)(s * (1.0f / 512.0f));
}

// ======== GCN: dual split-K GEMM (drug z=0, protein z=1) + dual epilogue ========
__global__ __launch_bounds__(256) void spk_gemm64_dual(
    const float* __restrict__ A0, const float* __restrict__ X0, float* __restrict__ P0, int M0, int kc0,
    const float* __restrict__ A1, const float* __restrict__ X1, float* __restrict__ P1, int M1, int kc1, int nx1)
{
    const float* A; const float* X; float* part; int M, kchunk;
    if (blockIdx.z == 0) { A = A0; X = X0; part = P0; M = M0; kchunk = kc0; }
    else { if ((int)blockIdx.x >= nx1) return; A = A1; X = X1; part = P1; M = M1; kchunk = kc1; }

    __shared__ float As[64][17];
    __shared__ float Xs[16][64];
    const int rb = blockIdx.x * 64;
    const int s = blockIdx.y;
    const int k0 = s * kchunk;
    const int k1 = (k0 + kchunk < M) ? (k0 + kchunk) : M;
    const int tid = threadIdx.x, tx = tid & 15, ty = tid >> 4;
    float acc[4][4] = {};
    for (int kb = k0; kb < k1; kb += 16) {
        #pragma unroll
        for (int q = 0; q < 4; ++q) {
            int r = (tid >> 4) + q * 16, kc = tid & 15;
            int row = rb + r, kidx = kb + kc;
            As[r][kc] = (row < M && kidx < k1) ? A[(size_t)row * M + kidx] : 0.f;
        }
        #pragma unroll
        for (int q = 0; q < 4; ++q) {
            int kr = (tid >> 6) + q * 4, cc = tid & 63;
            int kidx = kb + kr;
            Xs[kr][cc] = (kidx < k1) ? X[(size_t)kidx * 64 + cc] : 0.f;
        }
        __syncthreads();
        #pragma unroll
        for (int kk = 0; kk < 16; ++kk) {
            float a0 = As[ty * 4 + 0][kk], a1 = As[ty * 4 + 1][kk];
            float a2 = As[ty * 4 + 2][kk], a3 = As[ty * 4 + 3][kk];
            float4 b4 = *(const float4*)&Xs[kk][tx * 4];
            acc[0][0] += a0 * b4.x; acc[0][1] += a0 * b4.y; acc[0][2] += a0 * b4.z; acc[0][3] += a0 * b4.w;
            acc[1][0] += a1 * b4.x; acc[1][1] += a1 * b4.y; acc[1][2] += a1 * b4.z; acc[1][3] += a1 * b4.w;
            acc[2][0] += a2 * b4.x; acc[2][1] += a2 * b4.y; acc[2][2] += a2 * b4.z; acc[2][3] += a2 * b4.w;
            acc[3][0] += a3 * b4.x; acc[3][1] += a3 * b4.y; acc[3][2] += a3 * b4.z; acc[3][3] += a3 * b4.w;
        }
        __syncthreads();
    }
    #pragma unroll
    for (int i = 0; i < 4; ++i) {
        int row = rb + ty * 4 + i;
        if (row < M)
            *(float4*)&part[((size_t)s * M + row) * 64 + tx * 4] =
                make_float4(acc[i][0], acc[i][1], acc[i][2], acc[i][3]);
    }
}

__global__ __launch_bounds__(256) void gcn_epi_dual(
    const float* __restrict__ P0, int M0, const float* __restrict__ W0, const float* __restrict__ b0,
    float* __restrict__ O0, _Float16* __restrict__ H0,
    const float* __restrict__ P1, int M1, const float* __restrict__ W1, const float* __restrict__ b1,
    float* __restrict__ O1, _Float16* __restrict__ H1, int nx1)
{
    const float* part; const float* W; const float* bias; float* Xout; _Float16* H; int M;
    if (blockIdx.z == 0) { part = P0; W = W0; bias = b0; Xout = O0; H = H0; M = M0; }
    else { if ((int)blockIdx.x >= nx1) return; part = P1; W = W1; bias = b1; Xout = O1; H = H1; M = M1; }

    __shared__ float Ys[64][68];
    __shared__ float Ws[64][64];
    const int rb = blockIdx.x * 64;
    const int tid = threadIdx.x;
    for (int j = tid; j < 4096; j += 256) Ws[j >> 6][j & 63] = W[j];
    for (int j = tid; j < 4096; j += 256) {
        int r = j >> 6, c = j & 63;
        float sum = 0.f;
        if (rb + r < M)
            for (int t = 0; t < 8; ++t) sum += part[((size_t)t * M + rb + r) * 64 + c];
        Ys[r][c] = sum;
    }
    __syncthreads();
    const int tx = tid & 15, ty = tid >> 4;
    float acc[4][4];
    #pragma unroll
    for (int i = 0; i < 4; ++i)
        #pragma unroll
        for (int j = 0; j < 4; ++j) acc[i][j] = bias[tx * 4 + j];
    for (int d = 0; d < 64; ++d) {
        float a0 = Ys[ty * 4 + 0][d], a1 = Ys[ty * 4 + 1][d];
        float a2 = Ys[ty * 4 + 2][d], a3 = Ys[ty * 4 + 3][d];
        float4 w4 = *(const float4*)&Ws[d][tx * 4];
        acc[0][0] += a0 * w4.x; acc[0][1] += a0 * w4.y; acc[0][2] += a0 * w4.z; acc[0][3] += a0 * w4.w;
        acc[1][0] += a1 * w4.x; acc[1][1] += a1 * w4.y; acc[1][2] += a1 * w4.z; acc[1][3] += a1 * w4.w;
        acc[2][0] += a2 * w4.x; acc[2][1] += a2 * w4.y; acc[2][2] += a2 * w4.z; acc[2][3] += a2 * w4.w;
        acc[3][0] += a3 * w4.x; acc[3][1] += a3 * w4.y; acc[3][2] += a3 * w4.z; acc[3][3] += a3 * w4.w;
    }
    #pragma unroll
    for (int i = 0; i < 4; ++i) {
        int row = rb + ty * 4 + i;
        if (row < M) {
            #pragma unroll
            for (int j = 0; j < 4; ++j) {
                float v = fmaxf(acc[i][j], 0.f);
                if (Xout) Xout[(size_t)row * 64 + tx * 4 + j] = v;
                if (H)    H[(size_t)row * 64 + tx * 4 + j] = (_Float16)v;
            }
        }
    }
}

// ======== MFMA MLP GEMM: C=relu(A@B+bias), A fp16 [M][K] (opt row-gather),
// Bt fp16 [N][K], C fp16 [M][N]. Wave = 16 rows x NT*16 cols; col-split via
// blockIdx.y for occupancy (grid x = M/64, y = N/(NT*16)). No LDS staging. ====
template<int NT, bool GATHER>
__global__ __launch_bounds__(256) void mfma_mlp(
    const _Float16* __restrict__ A0, const int* __restrict__ idx0,
    const _Float16* __restrict__ Bt0, const float* __restrict__ bias0, _Float16* __restrict__ C0,
    const _Float16* __restrict__ A1, const int* __restrict__ idx1,
    const _Float16* __restrict__ Bt1, const float* __restrict__ bias1, _Float16* __restrict__ C1,
    int K, int N)
{
    const _Float16* A; const int* idx; const _Float16* Bt; const float* bias; _Float16* C;
    if (blockIdx.z == 0) { A = A0; idx = idx0; Bt = Bt0; bias = bias0; C = C0; }
    else                 { A = A1; idx = idx1; Bt = Bt1; bias = bias1; C = C1; }
    const int tid = threadIdx.x, wid = tid >> 6, lane = tid & 63;
    const int m = lane & 15, g = lane >> 4;
    const int row0 = blockIdx.x * 64 + wid * 16;
    const int col0 = blockIdx.y * (NT * 16);
    size_t arow = GATHER ? (size_t)idx[row0 + m] : (size_t)(row0 + m);
    const _Float16* Ap = A + arow * (size_t)K + 8 * g;
    f32x4 acc[NT] = {};
    for (int kb = 0; kb < K; kb += 32) {
        half8_t af = *(const half8_t*)&Ap[kb];
        #pragma unroll
        for (int t = 0; t < NT; ++t) {
            half8_t bf = *(const half8_t*)&Bt[(size_t)(col0 + t * 16 + m) * K + kb + 8 * g];
            acc[t] = __builtin_amdgcn_mfma_f32_16x16x32_f16(af, bf, acc[t], 0, 0, 0);
        }
    }
    __shared__ float cb[4][16][17];
    const int rr = lane >> 2, c4 = (lane & 3) * 4;
    #pragma unroll
    for (int t = 0; t < NT; ++t) {
        #pragma unroll
        for (int j = 0; j < 4; ++j) cb[wid][4 * g + j][m] = acc[t][j];
        half4_t h;
        #pragma unroll
        for (int j = 0; j < 4; ++j)
            h[j] = (_Float16)fmaxf(cb[wid][rr][c4 + j] + bias[col0 + t * 16 + c4 + j], 0.f);
        *(half4_t*)&C[(size_t)(row0 + rr) * N + col0 + t * 16 + c4] = h;
    }
}

// head GEMM1 with fused concat: K=384 over 6 fp16 [.][64] sources, N=256,
// col-split via blockIdx.y (NT=2 -> y=8)
__global__ __launch_bounds__(256) void mfma_head1(
    const int* __restrict__ idx_c, const int* __restrict__ idx_p,
    const _Float16* __restrict__ ci, const _Float16* __restrict__ xc, const _Float16* __restrict__ fd,
    const _Float16* __restrict__ pi, const _Float16* __restrict__ xp, const _Float16* __restrict__ fp,
    const _Float16* __restrict__ Bt, const float* __restrict__ bias, _Float16* __restrict__ C)
{
    const int tid = threadIdx.x, wid = tid >> 6, lane = tid & 63;
    const int m = lane & 15, g = lane >> 4;
    const int row0 = blockIdx.x * 64 + wid * 16;
    const int col0 = blockIdx.y * 32;
    int ic = idx_c[row0 + m], ip = idx_p[row0 + m];
    const _Float16* segs[6] = {
        ci + (size_t)ic * 64 + 8 * g,  xc + (size_t)ic * 64 + 8 * g,
        fd + (size_t)(row0 + m) * 64 + 8 * g,
        pi + (size_t)ip * 64 + 8 * g,  xp + (size_t)ip * 64 + 8 * g,
        fp + (size_t)(row0 + m) * 64 + 8 * g };
    f32x4 acc[2] = {};
    #pragma unroll
    for (int kb = 0; kb < 384; kb += 32) {
        half8_t af = *(const half8_t*)&segs[kb / 64][kb & 63];   // kb static after unroll
        #pragma unroll
        for (int t = 0; t < 2; ++t) {
            half8_t bf = *(const half8_t*)&Bt[(size_t)(col0 + t * 16 + m) * 384 + kb + 8 * g];
            acc[t] = __builtin_amdgcn_mfma_f32_16x16x32_f16(af, bf, acc[t], 0, 0, 0);
        }
    }
    __shared__ float cb[4][16][17];
    const int rr = lane >> 2, c4 = (lane & 3) * 4;
    #pragma unroll
    for (int t = 0; t < 2; ++t) {
        #pragma unroll
        for (int j = 0; j < 4; ++j) cb[wid][4 * g + j][m] = acc[t][j];
        half4_t h;
        #pragma unroll
        for (int j = 0; j < 4; ++j)
            h[j] = (_Float16)fmaxf(cb[wid][rr][c4 + j] + bias[col0 + t * 16 + c4 + j], 0.f);
        *(half4_t*)&C[(size_t)(row0 + rr) * 256 + col0 + t * 16 + c4] = h;
    }
}

// head GEMM3 (K=256,N=256) with fused final 256x2 matmul + sigmoid
__global__ __launch_bounds__(256) void mfma_head3(
    const _Float16* __restrict__ A, const _Float16* __restrict__ Bt,
    const float* __restrict__ bias, const float* __restrict__ Wi, const float* __restrict__ bi,
    float* __restrict__ out)
{
    const int tid = threadIdx.x, wid = tid >> 6, lane = tid & 63;
    const int m = lane & 15, g = lane >> 4;
    const int row0 = blockIdx.x * 64 + wid * 16;
    const _Float16* Ap = A + (size_t)(row0 + m) * 256 + 8 * g;
    f32x4 acc[16] = {};
    for (int kb = 0; kb < 256; kb += 32) {
        half8_t af = *(const half8_t*)&Ap[kb];
        #pragma unroll
        for (int t = 0; t < 16; ++t) {
            half8_t bf = *(const half8_t*)&Bt[(size_t)(t * 16 + m) * 256 + kb + 8 * g];
            acc[t] = __builtin_amdgcn_mfma_f32_16x16x32_f16(af, bf, acc[t], 0, 0, 0);
        }
    }
    float p0[4] = {}, p1[4] = {};
    #pragma unroll
    for (int t = 0; t < 16; ++t) {
        float w0 = Wi[(t * 16 + m) * 2], w1 = Wi[(t * 16 + m) * 2 + 1];
        float bc = bias[t * 16 + m];
        #pragma unroll
        for (int j = 0; j < 4; ++j) {
            float v = fmaxf(acc[t][j] + bc, 0.f);
            p0[j] += v * w0; p1[j] += v * w1;
        }
    }
    #pragma unroll
    for (int d = 1; d < 16; d <<= 1) {
        #pragma unroll
        for (int j = 0; j < 4; ++j) {
            p0[j] += __shfl_xor(p0[j], d, 64);
            p1[j] += __shfl_xor(p1[j], d, 64);
        }
    }
    if (m == 0) {
        float B0 = bi[0], B1 = bi[1];
        #pragma unroll
        for (int j = 0; j < 4; ++j) {
            int r = row0 + 4 * g + j;
            out[r * 2 + 0] = 1.f / (1.f + expf(-(p0[j] + B0)));
            out[r * 2 + 1] = 1.f / (1.f + expf(-(p1[j] + B1)));
        }
    }
}

// ======================= launch =======================
extern "C" void kernel_launch(void* const* d_in, const int* in_sizes, int n_in,
                              void* d_out, int out_size, void* d_ws, size_t ws_size,
                              hipStream_t stream)
{
    const int*   idx_c        = (const int*)  d_in[0];
    const int*   idx_p        = (const int*)  d_in[1];
    const int*   compounds    = (const int*)  d_in[2];
    const int*   proteins     = (const int*)  d_in[3];
    const float* adjacencies  = (const float*)d_in[4];
    const float* A_c          = (const float*)d_in[5];
    const float* A_p          = (const float*)d_in[6];
    const float* embed_fp     = (const float*)d_in[7];
    const float* embed_word   = (const float*)d_in[8];
    const float* Xs_c         = (const float*)d_in[9];
    const float* Xs_p         = (const float*)d_in[10];
    const float* drug_feat    = (const float*)d_in[11];
    const float* protein_feat = (const float*)d_in[12];
    const float* W_gnn        = (const float*)d_in[13];
    const float* b_gnn        = (const float*)d_in[14];
    const float* K_cnn        = (const float*)d_in[15];
    const float* b_cnn        = (const float*)d_in[16];
    const float* W_gcn_d      = (const float*)d_in[17];
    const float* b_gcn_d      = (const float*)d_in[18];
    const float* W_gcn_p      = (const float*)d_in[19];
    const float* b_gcn_p      = (const float*)d_in[20];
    const float* Wd1 = (const float*)d_in[21]; const float* bd1 = (const float*)d_in[22];
    const float* Wd2 = (const float*)d_in[23]; const float* bd2 = (const float*)d_in[24];
    const float* Wd3 = (const float*)d_in[25]; const float* bd3 = (const float*)d_in[26];
    const float* Wp1 = (const float*)d_in[27]; const float* bp1 = (const float*)d_in[28];
    const float* Wp2 = (const float*)d_in[29]; const float* bp2 = (const float*)d_in[30];
    const float* Wp3 = (const float*)d_in[31]; const float* bp3 = (const float*)d_in[32];
    const float* Wo1 = (const float*)d_in[33]; const float* bo1 = (const float*)d_in[34];
    const float* Wo2 = (const float*)d_in[35]; const float* bo2 = (const float*)d_in[36];
    const float* Wo3 = (const float*)d_in[37]; const float* bo3 = (const float*)d_in[38];
    const float* W_int = (const float*)d_in[39]; const float* b_int = (const float*)d_in[40];

    float* ws = (float*)d_ws;
    float* prot_part = ws; ws += NP * 16 * 64;
    float* wtab_g    = ws; ws += 8448;
    float* ehp_g     = ws; ws += NW * 40;
    float* part_c    = ws; ws += 8 * NC * 64;
    float* part_p    = ws; ws += 8 * NP * 64;
    float* Xc_a = ws; ws += NC * 64;
    float* Xp_a = ws; ws += NP * 64;
    // fp16 buffers (sizes in float units = halves/2)
    _Float16* comp_h  = (_Float16*)ws; ws += NC * 32;
    _Float16* prot_h  = (_Float16*)ws; ws += NP * 32;
    _Float16* Xcb_h   = (_Float16*)ws; ws += NC * 32;
    _Float16* Xpb_h   = (_Float16*)ws; ws += NP * 32;
    _Float16* drug_h  = (_Float16*)ws; ws += NC * 512;
    _Float16* protf_h = (_Float16*)ws; ws += NP * 512;
    _Float16* wd1t = (_Float16*)ws; ws += 65536;
    _Float16* wd2t = (_Float16*)ws; ws += 4096;
    _Float16* wd3t = (_Float16*)ws; ws += 2048;
    _Float16* wp1t = (_Float16*)ws; ws += 65536;
    _Float16* wp2t = (_Float16*)ws; ws += 4096;
    _Float16* wp3t = (_Float16*)ws; ws += 2048;
    _Float16* wo1t = (_Float16*)ws; ws += 49152;
    _Float16* wo2t = (_Float16*)ws; ws += 32768;
    _Float16* wo3t = (_Float16*)ws; ws += 32768;
    _Float16* fd1h = (_Float16*)ws; ws += BSZ * 64;
    _Float16* fd2h = (_Float16*)ws; ws += BSZ * 32;
    _Float16* fd3h = (_Float16*)ws; ws += BSZ * 32;
    _Float16* fp1h = (_Float16*)ws; ws += BSZ * 64;
    _Float16* fp2h = (_Float16*)ws; ws += BSZ * 32;
    _Float16* fp3h = (_Float16*)ws; ws += BSZ * 32;
    _Float16* h1h  = (_Float16*)ws; ws += BSZ * 128;
    _Float16* h2h  = (_Float16*)ws; ws += BSZ * 128;
    (void)ws_size; (void)in_sizes; (void)n_in; (void)out_size;

    // one-time prep
    cnn_prep<<<(16896 + NW * 80 + 255) / 256, 256, 0, stream>>>(
        K_cnn, (_Float16*)wtab_g, embed_word, (_Float16*)ehp_g);
    prep_h<<<(4100096 + 255) / 256, 256, 0, stream>>>(
        drug_feat, protein_feat, Wd1, Wd2, Wd3, Wp1, Wp2, Wp3, Wo1, Wo2, Wo3,
        drug_h, protf_h, wd1t, wd2t, wd3t, wp1t, wp2t, wp3t, wo1t, wo2t, wo3t);
    // branch 1: compound GNN
    gnn_kernel<<<NC, 320, 0, stream>>>(compounds, adjacencies, embed_fp, W_gnn, b_gnn, comp_h);
    // branch 2: protein CNN
    cnn_kernel<<<dim3(16, NP), 256, 0, stream>>>(proteins, (const _Float16*)ehp_g,
                                                 (const half8_t*)wtab_g, b_cnn, prot_part);
    cnn_reduce<<<NP, 64, 0, stream>>>(prot_part, prot_h);
    // branch 3: GCN drug+protein
    spk_gemm64_dual<<<dim3(32, 8, 2), 256, 0, stream>>>(
        A_c, Xs_c, part_c, NC, 256, A_p, Xs_p, part_p, NP, 192, 24);
    gcn_epi_dual<<<dim3(32, 1, 2), 256, 0, stream>>>(
        part_c, NC, W_gcn_d, b_gcn_d, Xc_a, nullptr,
        part_p, NP, W_gcn_p, b_gcn_p, Xp_a, nullptr, 24);
    spk_gemm64_dual<<<dim3(32, 8, 2), 256, 0, stream>>>(
        A_c, Xc_a, part_c, NC, 256, A_p, Xp_a, part_p, NP, 192, 24);
    gcn_epi_dual<<<dim3(32, 1, 2), 256, 0, stream>>>(
        part_c, NC, W_gcn_d + 4096, b_gcn_d + 64, nullptr, Xcb_h,
        part_p, NP, W_gcn_p + 4096, b_gcn_p + 64, nullptr, Xpb_h, 24);
    // branches 4+5: annotation MLPs (MFMA, dual, col-split grids)
    mfma_mlp<2, true ><<<dim3(64, 4, 2), 256, 0, stream>>>(
        drug_h, idx_c, wd1t, bd1, fd1h, protf_h, idx_p, wp1t, bp1, fp1h, 1024, 128);
    mfma_mlp<1, false><<<dim3(64, 4, 2), 256, 0, stream>>>(
        fd1h, nullptr, wd2t, bd2, fd2h, fp1h, nullptr, wp2t, bp2, fp2h, 128, 64);
    mfma_mlp<1, false><<<dim3(64, 4, 2), 256, 0, stream>>>(
        fd2h, nullptr, wd3t, bd3, fd3h, fp2h, nullptr, wp3t, bp3, fp3h, 64, 64);
    // head (MFMA): concat-fused GEMM1, GEMM2, GEMM3+final
    mfma_head1<<<dim3(64, 8), 256, 0, stream>>>(idx_c, idx_p, comp_h, Xcb_h, fd3h,
                                                prot_h, Xpb_h, fp3h, wo1t, bo1, h1h);
    mfma_mlp<2, false><<<dim3(64, 8, 1), 256, 0, stream>>>(
        h1h, nullptr, wo2t, bo2, h2h, h1h, nullptr, wo2t, bo2, h2h, 256, 256);
    mfma_head3<<<64, 256, 0, stream>>>(h2h, wo3t, bo3, W_int, b_int, (float*)d_out);
}

// Round 14
// 435.282 us; speedup vs baseline: 1.3600x; 1.1291x over previous
//
#include <hip/hip_runtime.h>
#include <math.h>

#define NC 2000
#define NP 1500
#define NA 40
#define LP 512
#define BSZ 4096
#define NW 8000
#define KPC 2048   // padded K for drug GCN (A_c 2000 -> 2048)
#define KPP 1536   // padded K for protein GCN (A_p 1500 -> 1536)

typedef _Float16 half8_t __attribute__((ext_vector_type(8)));
typedef _Float16 half4_t __attribute__((ext_vector_type(4)));
typedef float f32x4 __attribute__((ext_vector_type(4)));

// ======================= GNN (fused per compound) =======================
__global__ __launch_bounds__(320) void gnn_kernel(
    const int* __restrict__ compounds, const float* __restrict__ adjacencies,
    const float* __restrict__ embed_fp, const float* __restrict__ W_gnn,
    const float* __restrict__ b_gnn, _Float16* __restrict__ comp_h)
{
    __shared__ float xs[40][68];
    __shared__ float hs[40][68];
    __shared__ float Ws[64][64];
    __shared__ float adjS[40][41];
    __shared__ float bS[64];
    const int n = blockIdx.x;
    const int tid = threadIdx.x;
    const int a = tid >> 3, g = tid & 7, cb = g * 8;

    for (int j = tid; j < 40 * 64; j += 320) {
        int r = j >> 6, c = j & 63;
        xs[r][c] = embed_fp[(size_t)compounds[n * NA + r] * 64 + c];
    }
    for (int j = tid; j < NA * NA; j += 320)
        adjS[j / NA][j % NA] = adjacencies[(size_t)n * (NA * NA) + j];

    for (int l = 0; l < 3; ++l) {
        __syncthreads();
        for (int j = tid; j < 4096; j += 320) Ws[j >> 6][j & 63] = W_gnn[l * 4096 + j];
        if (tid < 64) bS[tid] = b_gnn[l * 64 + tid];
        __syncthreads();
        float acc[8];
        #pragma unroll
        for (int j = 0; j < 8; ++j) acc[j] = bS[cb + j];
        #pragma unroll 8
        for (int d = 0; d < 64; ++d) {
            float x = xs[a][d];
            float4 w0 = *(const float4*)&Ws[d][cb];
            float4 w1 = *(const float4*)&Ws[d][cb + 4];
            acc[0] += x * w0.x; acc[1] += x * w0.y; acc[2] += x * w0.z; acc[3] += x * w0.w;
            acc[4] += x * w1.x; acc[5] += x * w1.y; acc[6] += x * w1.z; acc[7] += x * w1.w;
        }
        #pragma unroll
        for (int j = 0; j < 8; ++j) hs[a][cb + j] = fmaxf(acc[j], 0.f);
        __syncthreads();
        float4 x0 = *(float4*)&xs[a][cb];
        float4 x1 = *(float4*)&xs[a][cb + 4];
        #pragma unroll 8
        for (int b = 0; b < NA; ++b) {
            float ad = adjS[a][b];
            float4 h0 = *(const float4*)&hs[b][cb];
            float4 h1 = *(const float4*)&hs[b][cb + 4];
            x0.x += ad * h0.x; x0.y += ad * h0.y; x0.z += ad * h0.z; x0.w += ad * h0.w;
            x1.x += ad * h1.x; x1.y += ad * h1.y; x1.z += ad * h1.z; x1.w += ad * h1.w;
        }
        *(float4*)&xs[a][cb] = x0;
        *(float4*)&xs[a][cb + 4] = x1;
    }
    __syncthreads();
    if (tid < 64) {
        float s = 0.f;
        for (int r = 0; r < NA; ++r) s += xs[r][tid];
        comp_h[n * 64 + tid] = (_Float16)(s * (1.0f / 40.0f));
    }
}

// ======================= CNN via MFMA (banded 16x16x32 f16) =======================
__device__ __forceinline__ int swz_off(int row, int half_col)
{
    int b = half_col >> 3;
    return row * 128 + (((b & 8) | ((b ^ row) & 7)) << 3) + (half_col & 7);
}

// one-time: wtab (16896 halves) + padded fp16 embed (NW*80)
__global__ void cnn_prep(const float* __restrict__ K_cnn, _Float16* __restrict__ wtab,
                         const float* __restrict__ ew, _Float16* __restrict__ ehp)
{
    int j = blockIdx.x * 256 + threadIdx.x;
    if (j < 16896) {
        int L = j / 5632, rem = j % 5632;
        int dr = rem >> 9, r2 = rem & 511, ln = r2 >> 3, i = r2 & 7;
        int dc = 8 * (ln >> 4) + i - (ln & 15);   // k - n
        float v = (dc >= 0 && dc < 11) ? K_cnn[L * 121 + dr * 11 + dc] : 0.f;
        wtab[j] = (_Float16)v;
        return;
    }
    int e = j - 16896;
    if (e >= NW * 80) return;
    int w = e / 80, h = e - w * 80;
    float v = (h >= 13 && h < 77) ? ew[w * 64 + (h - 13)] : 0.f;
    ehp[e] = (_Float16)v;
}

// one-time: fp16 feature copies + fp16 transposed weights [N][K]
__global__ void prep_h(
    const float* __restrict__ df, const float* __restrict__ pf,
    const float* __restrict__ wd1, const float* __restrict__ wd2, const float* __restrict__ wd3,
    const float* __restrict__ wp1, const float* __restrict__ wp2, const float* __restrict__ wp3,
    const float* __restrict__ wo1, const float* __restrict__ wo2, const float* __restrict__ wo3,
    _Float16* __restrict__ dfh, _Float16* __restrict__ pfh,
    _Float16* __restrict__ wd1t, _Float16* __restrict__ wd2t, _Float16* __restrict__ wd3t,
    _Float16* __restrict__ wp1t, _Float16* __restrict__ wp2t, _Float16* __restrict__ wp3t,
    _Float16* __restrict__ wo1t, _Float16* __restrict__ wo2t, _Float16* __restrict__ wo3t)
{
    int j = blockIdx.x * 256 + threadIdx.x;
    if (j < 2048000) { dfh[j] = (_Float16)df[j]; return; }
    j -= 2048000;
    if (j < 1536000) { pfh[j] = (_Float16)pf[j]; return; }
    j -= 1536000;
    if (j < 131072) { int n = j >> 10, k = j & 1023; wd1t[j] = (_Float16)wd1[k * 128 + n]; return; }
    j -= 131072;
    if (j < 8192)  { int n = j >> 7, k = j & 127; wd2t[j] = (_Float16)wd2[k * 64 + n]; return; }
    j -= 8192;
    if (j < 4096)  { int n = j >> 6, k = j & 63; wd3t[j] = (_Float16)wd3[k * 64 + n]; return; }
    j -= 4096;
    if (j < 131072) { int n = j >> 10, k = j & 1023; wp1t[j] = (_Float16)wp1[k * 128 + n]; return; }
    j -= 131072;
    if (j < 8192)  { int n = j >> 7, k = j & 127; wp2t[j] = (_Float16)wp2[k * 64 + n]; return; }
    j -= 8192;
    if (j < 4096)  { int n = j >> 6, k = j & 63; wp3t[j] = (_Float16)wp3[k * 64 + n]; return; }
    j -= 4096;
    if (j < 98304) { int n = j / 384, k = j - n * 384; wo1t[j] = (_Float16)wo1[k * 256 + n]; return; }
    j -= 98304;
    if (j < 65536) { int n = j >> 8, k = j & 255; wo2t[j] = (_Float16)wo2[k * 256 + n]; return; }
    j -= 65536;
    if (j < 65536) { int n = j >> 8, k = j & 255; wo3t[j] = (_Float16)wo3[k * 256 + n]; return; }
}

// one-time: fp16 padded adjacency [Kpad][Kpad] + transposed fp16 X [64][Kpad];
// zero inter-layer Xt buffers (pad rows must be 0)
__global__ void gcn_prep(
    const float* __restrict__ Ac, const float* __restrict__ Ap,
    const float* __restrict__ Xc, const float* __restrict__ Xp,
    _Float16* __restrict__ Ahc, _Float16* __restrict__ Ahp,
    _Float16* __restrict__ Xtc, _Float16* __restrict__ Xtp,
    _Float16* __restrict__ Xtca, _Float16* __restrict__ Xtpa)
{
    int j = blockIdx.x * 256 + threadIdx.x;
    if (j < KPC * KPC) {
        int r = j >> 11, c = j & (KPC - 1);
        Ahc[j] = (_Float16)((r < NC && c < NC) ? Ac[(size_t)r * NC + c] : 0.f);
        return;
    }
    j -= KPC * KPC;
    if (j < KPP * KPP) {
        int r = j / KPP, c = j - r * KPP;
        Ahp[j] = (_Float16)((r < NP && c < NP) ? Ap[(size_t)r * NP + c] : 0.f);
        return;
    }
    j -= KPP * KPP;
    if (j < 64 * KPC) {
        int c = j >> 11, r = j & (KPC - 1);
        Xtc[j] = (_Float16)((r < NC) ? Xc[(size_t)r * 64 + c] : 0.f);
        return;
    }
    j -= 64 * KPC;
    if (j < 64 * KPP) {
        int c = j / KPP, r = j - c * KPP;
        Xtp[j] = (_Float16)((r < NP) ? Xp[(size_t)r * 64 + c] : 0.f);
        return;
    }
    j -= 64 * KPP;
    if (j < 64 * KPC) { Xtca[j] = (_Float16)0.f; return; }
    j -= 64 * KPC;
    if (j < 64 * KPP) { Xtpa[j] = (_Float16)0.f; }
}

__global__ __launch_bounds__(256) void cnn_kernel(
    const int* __restrict__ proteins, const _Float16* __restrict__ ehp,
    const half8_t* __restrict__ wtab, const float* __restrict__ b_cnn,
    float* __restrict__ prot_part)
{
    __shared__ half8_t bufA8[62 * 16];
    __shared__ half8_t bufB8[62 * 16];
    _Float16* bufA = (_Float16*)bufA8;
    _Float16* bufB = (_Float16*)bufB8;

    const int tile = blockIdx.x, p = blockIdx.y;
    const int t0 = tile * 32, tid = threadIdx.x;
    const int lane = tid & 63, wid = tid >> 6;
    const int c0 = wid * 16;
    const int m = lane & 15, g = lane >> 4;

    half8_t z = {};
    for (int e = tid; e < 62 * 9; e += 256) {
        int i = e / 9, a = 1 + (e - 9 * i);
        int gr = t0 - 15 + i;
        half8_t v = z;
        if (gr >= 0 && gr < LP)
            v = *(const half8_t*)&ehp[(size_t)proteins[p * LP + gr] * 80 + 8 * a];
        *(half8_t*)&bufA[i * 128 + (((a & 8) | ((a ^ i) & 7)) << 3)] = v;
    }
    // zero read-but-never-stored blocks: bufA blk10; bufB blk1, blk9, blk10
    for (int e = tid; e < 62 * 4; e += 256) {
        int i = e >> 2, w = e & 3;
        if (w == 0)      bufA8[i * 16 + (8 | ((10 ^ i) & 7))] = z;
        else if (w == 1) bufB8[i * 16 + ((1 ^ i) & 7)] = z;
        else {
            int blk = 7 + w;
            bufB8[i * 16 + ((blk & 8) | ((blk ^ i) & 7))] = z;
        }
    }

    half8_t wf[11];
    auto load_wf = [&](int L) {
        #pragma unroll
        for (int dr = 0; dr < 11; ++dr) wf[dr] = wtab[L * 11 * 64 + dr * 64 + lane];
    };
    auto conv_tile = [&](const _Float16* src, int r0, float bias) -> f32x4 {
        f32x4 acc = {bias, bias, bias, bias};
        const int B0 = (c0 + 8) >> 3;
        #pragma unroll
        for (int dr = 0; dr < 11; ++dr) {
            int R = r0 - 5 + dr + m;
            int b = B0 + g;
            half8_t a = *(const half8_t*)&src[R * 128 + (((b & 8) | ((b ^ R) & 7)) << 3)];
            acc = __builtin_amdgcn_mfma_f32_16x16x32_f16(a, wf[dr], acc, 0, 0, 0);
        }
        return acc;
    };
    auto store_tile = [&](_Float16* dst, int r0, f32x4 acc) {
        int pc = c0 + 13 + m;
        #pragma unroll
        for (int j = 0; j < 4; ++j) {
            int row = r0 + 4 * g + j;
            int og = t0 - 15 + row;
            float v = fmaxf(acc[j], 0.f);
            dst[swz_off(row, pc)] = (_Float16)((og >= 0 && og < LP) ? v : 0.f);
        }
    };

    load_wf(0);
    __syncthreads();
    {
        float b0 = b_cnn[0];
        const int r0s[4] = {5, 21, 37, 41};
        #pragma unroll
        for (int k = 0; k < 4; ++k) store_tile(bufB, r0s[k], conv_tile(bufA, r0s[k], b0));
    }
    __syncthreads();
    load_wf(1);
    {
        float b1 = b_cnn[1];
        const int r0s[3] = {10, 26, 36};
        #pragma unroll
        for (int k = 0; k < 3; ++k) store_tile(bufA, r0s[k], conv_tile(bufB, r0s[k], b1));
    }
    __syncthreads();
    load_wf(2);
    {
        float b2 = b_cnn[2];
        float cs = 0.f;
        const int r0s[2] = {15, 31};
        #pragma unroll
        for (int k = 0; k < 2; ++k) {
            f32x4 acc = conv_tile(bufA, r0s[k], b2);
            #pragma unroll
            for (int j = 0; j < 4; ++j) cs += fmaxf(acc[j], 0.f);
        }
        cs += __shfl_xor(cs, 16, 64);
        cs += __shfl_xor(cs, 32, 64);
        if (lane < 16)
            prot_part[((size_t)p * 16 + tile) * 64 + c0 + lane] = cs;
    }
}

__global__ void cnn_reduce(const float* __restrict__ prot_part, _Float16* __restrict__ prot_h)
{
    const int p = blockIdx.x, c = threadIdx.x;
    float s = 0.f;
    for (int t = 0; t < 16; ++t) s += prot_part[((size_t)p * 16 + t) * 64 + c];
    prot_h[p * 64 + c] = (_Float16)(s * (1.0f / 512.0f));
}

// ======== GCN: MFMA split-K GEMM part = A@X (drug z=0, protein z=1) ========
// A fp16 [Kpad][Kpad] row-major (zero-padded), Xt fp16 [64][Kpad] (B^T),
// wave = 16 rows x 64 cols, split-K via blockIdx.y (8 chunks).
__global__ __launch_bounds__(256) void spk_mfma_dual(
    const _Float16* __restrict__ Ah0, const _Float16* __restrict__ Xt0, float* __restrict__ P0, int M0, int Kp0,
    const _Float16* __restrict__ Ah1, const _Float16* __restrict__ Xt1, float* __restrict__ P1, int M1, int Kp1,
    int nx1)
{
    const _Float16* Ah; const _Float16* Xt; float* part; int M, Kp;
    if (blockIdx.z == 0) { Ah = Ah0; Xt = Xt0; part = P0; M = M0; Kp = Kp0; }
    else { if ((int)blockIdx.x >= nx1) return; Ah = Ah1; Xt = Xt1; part = P1; M = M1; Kp = Kp1; }

    const int tid = threadIdx.x, wid = tid >> 6, lane = tid & 63;
    const int m = lane & 15, g = lane >> 4;
    const int row0 = blockIdx.x * 64 + wid * 16;
    const int chunk = Kp >> 3, k0 = blockIdx.y * chunk;
    const _Float16* Apr = Ah + (size_t)(row0 + m) * Kp + 8 * g;
    f32x4 acc[4] = {};
    for (int kb = k0; kb < k0 + chunk; kb += 32) {
        half8_t af = *(const half8_t*)&Apr[kb];
        #pragma unroll
        for (int t = 0; t < 4; ++t) {
            half8_t bf = *(const half8_t*)&Xt[(size_t)(t * 16 + m) * Kp + kb + 8 * g];
            acc[t] = __builtin_amdgcn_mfma_f32_16x16x32_f16(af, bf, acc[t], 0, 0, 0);
        }
    }
    const int s = blockIdx.y;
    #pragma unroll
    for (int t = 0; t < 4; ++t)
        #pragma unroll
        for (int j = 0; j < 4; ++j) {
            int row = row0 + 4 * g + j;
            if (row < M) part[((size_t)s * M + row) * 64 + t * 16 + m] = acc[t][j];
        }
}

// epilogue: sum 8 partials, @W + bias + relu; outputs nullable:
// H (fp16 row-major [M][64]) and/or XtN (fp16 transposed [64][Kpad], pre-zeroed pads)
__global__ __launch_bounds__(256) void gcn_epi_dual(
    const float* __restrict__ P0, int M0, const float* __restrict__ W0, const float* __restrict__ b0,
    _Float16* __restrict__ H0, _Float16* __restrict__ XtN0, int Kp0,
    const float* __restrict__ P1, int M1, const float* __restrict__ W1, const float* __restrict__ b1,
    _Float16* __restrict__ H1, _Float16* __restrict__ XtN1, int Kp1, int nx1)
{
    const float* part; const float* W; const float* bias; _Float16* H; _Float16* XtN; int M, Kp;
    if (blockIdx.z == 0) { part = P0; W = W0; bias = b0; H = H0; XtN = XtN0; M = M0; Kp = Kp0; }
    else { if ((int)blockIdx.x >= nx1) return; part = P1; W = W1; bias = b1; H = H1; XtN = XtN1; M = M1; Kp = Kp1; }

    __shared__ float Ys[64][68];
    __shared__ float Ws[64][64];
    const int rb = blockIdx.x * 64;
    const int tid = threadIdx.x;
    for (int j = tid; j < 4096; j += 256) Ws[j >> 6][j & 63] = W[j];
    for (int j = tid; j < 4096; j += 256) {
        int r = j >> 6, c = j & 63;
        float sum = 0.f;
        if (rb + r < M)
            for (int t = 0; t < 8; ++t) sum += part[((size_t)t * M + rb + r) * 64 + c];
        Ys[r][c] = sum;
    }
    __syncthreads();
    const int tx = tid & 15, ty = tid >> 4;
    float acc[4][4];
    #pragma unroll
    for (int i = 0; i < 4; ++i)
        #pragma unroll
        for (int j = 0; j < 4; ++j) acc[i][j] = bias[tx * 4 + j];
    for (int d = 0; d < 64; ++d) {
        float a0 = Ys[ty * 4 + 0][d], a1 = Ys[ty * 4 + 1][d];
        float a2 = Ys[ty * 4 + 2][d], a3 = Ys[ty * 4 + 3][d];
        float4 w4 = *(const float4*)&Ws[d][tx * 4];
        acc[0][0] += a0 * w4.x; acc[0][1] += a0 * w4.y; acc[0][2] += a0 * w4.z; acc[0][3] += a0 * w4.w;
        acc[1][0] += a1 * w4.x; acc[1][1] += a1 * w4.y; acc[1][2] += a1 * w4.z; acc[1][3] += a1 * w4.w;
        acc[2][0] += a2 * w4.x; acc[2][1] += a2 * w4.y; acc[2][2] += a2 * w4.z; acc[2][3] += a2 * w4.w;
        acc[3][0] += a3 * w4.x; acc[3][1] += a3 * w4.y; acc[3][2] += a3 * w4.z; acc[3][3] += a3 * w4.w;
    }
    #pragma unroll
    for (int i = 0; i < 4; ++i) {
        int row = rb + ty * 4 + i;
        if (row < M) {
            #pragma unroll
            for (int j = 0; j < 4; ++j) {
                int col = tx * 4 + j;
                float v = fmaxf(acc[i][j], 0.f);
                if (H)   H[(size_t)row * 64 + col] = (_Float16)v;
                if (XtN) XtN[(size_t)col * Kp + row] = (_Float16)v;
            }
        }
    }
}

// ======== MFMA MLP GEMM: C=relu(A@B+bias), A fp16 [M][K] (opt row-gather),
// Bt fp16 [N][K], C fp16 [M][N]. Wave = 16 rows x NT*16 cols; col-split via
// blockIdx.y for occupancy. No LDS staging. ====
template<int NT, bool GATHER>
__global__ __launch_bounds__(256) void mfma_mlp(
    const _Float16* __restrict__ A0, const int* __restrict__ idx0,
    const _Float16* __restrict__ Bt0, const float* __restrict__ bias0, _Float16* __restrict__ C0,
    const _Float16* __restrict__ A1, const int* __restrict__ idx1,
    const _Float16* __restrict__ Bt1, const float* __restrict__ bias1, _Float16* __restrict__ C1,
    int K, int N)
{
    const _Float16* A; const int* idx; const _Float16* Bt; const float* bias; _Float16* C;
    if (blockIdx.z == 0) { A = A0; idx = idx0; Bt = Bt0; bias = bias0; C = C0; }
    else                 { A = A1; idx = idx1; Bt = Bt1; bias = bias1; C = C1; }
    const int tid = threadIdx.x, wid = tid >> 6, lane = tid & 63;
    const int m = lane & 15, g = lane >> 4;
    const int row0 = blockIdx.x * 64 + wid * 16;
    const int col0 = blockIdx.y * (NT * 16);
    size_t arow = GATHER ? (size_t)idx[row0 + m] : (size_t)(row0 + m);
    const _Float16* Ap = A + arow * (size_t)K + 8 * g;
    f32x4 acc[NT] = {};
    for (int kb = 0; kb < K; kb += 32) {
        half8_t af = *(const half8_t*)&Ap[kb];
        #pragma unroll
        for (int t = 0; t < NT; ++t) {
            half8_t bf = *(const half8_t*)&Bt[(size_t)(col0 + t * 16 + m) * K + kb + 8 * g];
            acc[t] = __builtin_amdgcn_mfma_f32_16x16x32_f16(af, bf, acc[t], 0, 0, 0);
        }
    }
    __shared__ float cb[4][16][17];
    const int rr = lane >> 2, c4 = (lane & 3) * 4;
    #pragma unroll
    for (int t = 0; t < NT; ++t) {
        #pragma unroll
        for (int j = 0; j < 4; ++j) cb[wid][4 * g + j][m] = acc[t][j];
        half4_t h;
        #pragma unroll
        for (int j = 0; j < 4; ++j)
            h[j] = (_Float16)fmaxf(cb[wid][rr][c4 + j] + bias[col0 + t * 16 + c4 + j], 0.f);
        *(half4_t*)&C[(size_t)(row0 + rr) * N + col0 + t * 16 + c4] = h;
    }
}

// head GEMM1 with fused concat: K=384 over 6 fp16 [.][64] sources, N=256
__global__ __launch_bounds__(256) void mfma_head1(
    const int* __restrict__ idx_c, const int* __restrict__ idx_p,
    const _Float16* __restrict__ ci, const _Float16* __restrict__ xc, const _Float16* __restrict__ fd,
    const _Float16* __restrict__ pi, const _Float16* __restrict__ xp, const _Float16* __restrict__ fp,
    const _Float16* __restrict__ Bt, const float* __restrict__ bias, _Float16* __restrict__ C)
{
    const int tid = threadIdx.x, wid = tid >> 6, lane = tid & 63;
    const int m = lane & 15, g = lane >> 4;
    const int row0 = blockIdx.x * 64 + wid * 16;
    const int col0 = blockIdx.y * 32;
    int ic = idx_c[row0 + m], ip = idx_p[row0 + m];
    const _Float16* segs[6] = {
        ci + (size_t)ic * 64 + 8 * g,  xc + (size_t)ic * 64 + 8 * g,
        fd + (size_t)(row0 + m) * 64 + 8 * g,
        pi + (size_t)ip * 64 + 8 * g,  xp + (size_t)ip * 64 + 8 * g,
        fp + (size_t)(row0 + m) * 64 + 8 * g };
    f32x4 acc[2] = {};
    #pragma unroll
    for (int kb = 0; kb < 384; kb += 32) {
        half8_t af = *(const half8_t*)&segs[kb / 64][kb & 63];   // kb static after unroll
        #pragma unroll
        for (int t = 0; t < 2; ++t) {
            half8_t bf = *(const half8_t*)&Bt[(size_t)(col0 + t * 16 + m) * 384 + kb + 8 * g];
            acc[t] = __builtin_amdgcn_mfma_f32_16x16x32_f16(af, bf, acc[t], 0, 0, 0);
        }
    }
    __shared__ float cb[4][16][17];
    const int rr = lane >> 2, c4 = (lane & 3) * 4;
    #pragma unroll
    for (int t = 0; t < 2; ++t) {
        #pragma unroll
        for (int j = 0; j < 4; ++j) cb[wid][4 * g + j][m] = acc[t][j];
        half4_t h;
        #pragma unroll
        for (int j = 0; j < 4; ++j)
            h[j] = (_Float16)fmaxf(cb[wid][rr][c4 + j] + bias[col0 + t * 16 + c4 + j], 0.f);
        *(half4_t*)&C[(size_t)(row0 + rr) * 256 + col0 + t * 16 + c4] = h;
    }
}

// head GEMM3 (K=256,N=256) with fused final 256x2 matmul + sigmoid
__global__ __launch_bounds__(256) void mfma_head3(
    const _Float16* __restrict__ A, const _Float16* __restrict__ Bt,
    const float* __restrict__ bias, const float* __restrict__ Wi, const float* __restrict__ bi,
    float* __restrict__ out)
{
    const int tid = threadIdx.x, wid = tid >> 6, lane = tid & 63;
    const int m = lane & 15, g = lane >> 4;
    const int row0 = blockIdx.x * 64 + wid * 16;
    const _Float16* Ap = A + (size_t)(row0 + m) * 256 + 8 * g;
    f32x4 acc[16] = {};
    for (int kb = 0; kb < 256; kb += 32) {
        half8_t af = *(const half8_t*)&Ap[kb];
        #pragma unroll
        for (int t = 0; t < 16; ++t) {
            half8_t bf = *(const half8_t*)&Bt[(size_t)(t * 16 + m) * 256 + kb + 8 * g];
            acc[t] = __builtin_amdgcn_mfma_f32_16x16x32_f16(af, bf, acc[t], 0, 0, 0);
        }
    }
    float p0[4] = {}, p1[4] = {};
    #pragma unroll
    for (int t = 0; t < 16; ++t) {
        float w0 = Wi[(t * 16 + m) * 2], w1 = Wi[(t * 16 + m) * 2 + 1];
        float bc = bias[t * 16 + m];
        #pragma unroll
        for (int j = 0; j < 4; ++j) {
            float v = fmaxf(acc[t][j] + bc, 0.f);
            p0[j] += v * w0; p1[j] += v * w1;
        }
    }
    #pragma unroll
    for (int d = 1; d < 16; d <<= 1) {
        #pragma unroll
        for (int j = 0; j < 4; ++j) {
            p0[j] += __shfl_xor(p0[j], d, 64);
            p1[j] += __shfl_xor(p1[j], d, 64);
        }
    }
    if (m == 0) {
        float B0 = bi[0], B1 = bi[1];
        #pragma unroll
        for (int j = 0; j < 4; ++j) {
            int r = row0 + 4 * g + j;
            out[r * 2 + 0] = 1.f / (1.f + expf(-(p0[j] + B0)));
            out[r * 2 + 1] = 1.f / (1.f + expf(-(p1[j] + B1)));
        }
    }
}

// ======================= launch =======================
extern "C" void kernel_launch(void* const* d_in, const int* in_sizes, int n_in,
                              void* d_out, int out_size, void* d_ws, size_t ws_size,
                              hipStream_t stream)
{
    const int*   idx_c        = (const int*)  d_in[0];
    const int*   idx_p        = (const int*)  d_in[1];
    const int*   compounds    = (const int*)  d_in[2];
    const int*   proteins     = (const int*)  d_in[3];
    const float* adjacencies  = (const float*)d_in[4];
    const float* A_c          = (const float*)d_in[5];
    const float* A_p          = (const float*)d_in[6];
    const float* embed_fp     = (const float*)d_in[7];
    const float* embed_word   = (const float*)d_in[8];
    const float* Xs_c         = (const float*)d_in[9];
    const float* Xs_p         = (const float*)d_in[10];
    const float* drug_feat    = (const float*)d_in[11];
    const float* protein_feat = (const float*)d_in[12];
    const float* W_gnn        = (const float*)d_in[13];
    const float* b_gnn        = (const float*)d_in[14];
    const float* K_cnn        = (const float*)d_in[15];
    const float* b_cnn        = (const float*)d_in[16];
    const float* W_gcn_d      = (const float*)d_in[17];
    const float* b_gcn_d      = (const float*)d_in[18];
    const float* W_gcn_p      = (const float*)d_in[19];
    const float* b_gcn_p      = (const float*)d_in[20];
    const float* Wd1 = (const float*)d_in[21]; const float* bd1 = (const float*)d_in[22];
    const float* Wd2 = (const float*)d_in[23]; const float* bd2 = (const float*)d_in[24];
    const float* Wd3 = (const float*)d_in[25]; const float* bd3 = (const float*)d_in[26];
    const float* Wp1 = (const float*)d_in[27]; const float* bp1 = (const float*)d_in[28];
    const float* Wp2 = (const float*)d_in[29]; const float* bp2 = (const float*)d_in[30];
    const float* Wp3 = (const float*)d_in[31]; const float* bp3 = (const float*)d_in[32];
    const float* Wo1 = (const float*)d_in[33]; const float* bo1 = (const float*)d_in[34];
    const float* Wo2 = (const float*)d_in[35]; const float* bo2 = (const float*)d_in[36];
    const float* Wo3 = (const float*)d_in[37]; const float* bo3 = (const float*)d_in[38];
    const float* W_int = (const float*)d_in[39]; const float* b_int = (const float*)d_in[40];

    float* ws = (float*)d_ws;
    float* prot_part = ws; ws += NP * 16 * 64;
    float* wtab_g    = ws; ws += 8448;
    float* ehp_g     = ws; ws += NW * 40;
    float* part_c    = ws; ws += 8 * NC * 64;
    float* part_p    = ws; ws += 8 * NP * 64;
    // fp16 buffers (sizes in float units = halves/2)
    _Float16* Ah_c  = (_Float16*)ws; ws += KPC * KPC / 2;
    _Float16* Ah_p  = (_Float16*)ws; ws += KPP * KPP / 2;
    _Float16* Xt_c  = (_Float16*)ws; ws += 32 * KPC;
    _Float16* Xt_p  = (_Float16*)ws; ws += 32 * KPP;
    _Float16* Xt_ca = (_Float16*)ws; ws += 32 * KPC;
    _Float16* Xt_pa = (_Float16*)ws; ws += 32 * KPP;
    _Float16* comp_h  = (_Float16*)ws; ws += NC * 32;
    _Float16* prot_h  = (_Float16*)ws; ws += NP * 32;
    _Float16* Xcb_h   = (_Float16*)ws; ws += NC * 32;
    _Float16* Xpb_h   = (_Float16*)ws; ws += NP * 32;
    _Float16* drug_h  = (_Float16*)ws; ws += NC * 512;
    _Float16* protf_h = (_Float16*)ws; ws += NP * 512;
    _Float16* wd1t = (_Float16*)ws; ws += 65536;
    _Float16* wd2t = (_Float16*)ws; ws += 4096;
    _Float16* wd3t = (_Float16*)ws; ws += 2048;
    _Float16* wp1t = (_Float16*)ws; ws += 65536;
    _Float16* wp2t = (_Float16*)ws; ws += 4096;
    _Float16* wp3t = (_Float16*)ws; ws += 2048;
    _Float16* wo1t = (_Float16*)ws; ws += 49152;
    _Float16* wo2t = (_Float16*)ws; ws += 32768;
    _Float16* wo3t = (_Float16*)ws; ws += 32768;
    _Float16* fd1h = (_Float16*)ws; ws += BSZ * 64;
    _Float16* fd2h = (_Float16*)ws; ws += BSZ * 32;
    _Float16* fd3h = (_Float16*)ws; ws += BSZ * 32;
    _Float16* fp1h = (_Float16*)ws; ws += BSZ * 64;
    _Float16* fp2h = (_Float16*)ws; ws += BSZ * 32;
    _Float16* fp3h = (_Float16*)ws; ws += BSZ * 32;
    _Float16* h1h  = (_Float16*)ws; ws += BSZ * 128;
    _Float16* h2h  = (_Float16*)ws; ws += BSZ * 128;
    (void)ws_size; (void)in_sizes; (void)n_in; (void)out_size;

    // one-time prep
    cnn_prep<<<(16896 + NW * 80 + 255) / 256, 256, 0, stream>>>(
        K_cnn, (_Float16*)wtab_g, embed_word, (_Float16*)ehp_g);
    prep_h<<<(4100096 + 255) / 256, 256, 0, stream>>>(
        drug_feat, protein_feat, Wd1, Wd2, Wd3, Wp1, Wp2, Wp3, Wo1, Wo2, Wo3,
        drug_h, protf_h, wd1t, wd2t, wd3t, wp1t, wp2t, wp3t, wo1t, wo2t, wo3t);
    {
        int total = KPC * KPC + KPP * KPP + 64 * KPC + 64 * KPP + 64 * KPC + 64 * KPP;
        gcn_prep<<<(total + 255) / 256, 256, 0, stream>>>(
            A_c, A_p, Xs_c, Xs_p, Ah_c, Ah_p, Xt_c, Xt_p, Xt_ca, Xt_pa);
    }
    // branch 1: compound GNN
    gnn_kernel<<<NC, 320, 0, stream>>>(compounds, adjacencies, embed_fp, W_gnn, b_gnn, comp_h);
    // branch 2: protein CNN
    cnn_kernel<<<dim3(16, NP), 256, 0, stream>>>(proteins, (const _Float16*)ehp_g,
                                                 (const half8_t*)wtab_g, b_cnn, prot_part);
    cnn_reduce<<<NP, 64, 0, stream>>>(prot_part, prot_h);
    // branch 3: GCN drug+protein (MFMA)
    spk_mfma_dual<<<dim3(32, 8, 2), 256, 0, stream>>>(
        Ah_c, Xt_c, part_c, NC, KPC, Ah_p, Xt_p, part_p, NP, KPP, 24);
    gcn_epi_dual<<<dim3(32, 1, 2), 256, 0, stream>>>(
        part_c, NC, W_gcn_d, b_gcn_d, nullptr, Xt_ca, KPC,
        part_p, NP, W_gcn_p, b_gcn_p, nullptr, Xt_pa, KPP, 24);
    spk_mfma_dual<<<dim3(32, 8, 2), 256, 0, stream>>>(
        Ah_c, Xt_ca, part_c, NC, KPC, Ah_p, Xt_pa, part_p, NP, KPP, 24);
    gcn_epi_dual<<<dim3(32, 1, 2), 256, 0, stream>>>(
        part_c, NC, W_gcn_d + 4096, b_gcn_d + 64, Xcb_h, nullptr, KPC,
        part_p, NP, W_gcn_p + 4096, b_gcn_p + 64, Xpb_h, nullptr, KPP, 24);
    // branches 4+5: annotation MLPs (MFMA, dual, col-split grids)
    mfma_mlp<2, true ><<<dim3(64, 4, 2), 256, 0, stream>>>(
        drug_h, idx_c, wd1t, bd1, fd1h, protf_h, idx_p, wp1t, bp1, fp1h, 1024, 128);
    mfma_mlp<1, false><<<dim3(64, 4, 2), 256, 0, stream>>>(
        fd1h, nullptr, wd2t, bd2, fd2h, fp1h, nullptr, wp2t, bp2, fp2h, 128, 64);
    mfma_mlp<1, false><<<dim3(64, 4, 2), 256, 0, stream>>>(
        fd2h, nullptr, wd3t, bd3, fd3h, fp2h, nullptr, wp3t, bp3, fp3h, 64, 64);
    // head (MFMA): concat-fused GEMM1, GEMM2, GEMM3+final
    mfma_head1<<<dim3(64, 8), 256, 0, stream>>>(idx_c, idx_p, comp_h, Xcb_h, fd3h,
                                                prot_h, Xpb_h, fp3h, wo1t, bo1, h1h);
    mfma_mlp<2, false><<<dim3(64, 8, 1), 256, 0, stream>>>(
        h1h, nullptr, wo2t, bo2, h2h, h1h, nullptr, wo2t, bo2, h2h, 256, 256);
    mfma_head3<<<64, 256, 0, stream>>>(h2h, wo3t, bo3, W_int, b_int, (float*)d_out);
}

// Round 15
// 424.195 us; speedup vs baseline: 1.3955x; 1.0261x over previous
//
#include <hip/hip_runtime.h>
#include <math.h>

#define NC 2000
#define NP 1500
#define NA 40
#define LP 512
#define BSZ 4096
#define NW 8000
#define KPC 2048   // padded K for drug GCN
#define KPP 1536   // padded K for protein GCN

typedef _Float16 half8_t __attribute__((ext_vector_type(8)));
typedef _Float16 half4_t __attribute__((ext_vector_type(4)));
typedef float f32x4 __attribute__((ext_vector_type(4)));

__device__ __forceinline__ int swz_off(int row, int half_col)
{
    int b = half_col >> 3;
    return row * 128 + (((b & 8) | ((b ^ row) & 7)) << 3) + (half_col & 7);
}

// =============== one-time prep: all fp16 tables/copies in one kernel ===============
__global__ void prep_all(
    const float* __restrict__ K_cnn, _Float16* __restrict__ wtab,
    const float* __restrict__ ew, _Float16* __restrict__ ehp,
    const float* __restrict__ df, const float* __restrict__ pf,
    const float* __restrict__ wd1, const float* __restrict__ wd2, const float* __restrict__ wd3,
    const float* __restrict__ wp1, const float* __restrict__ wp2, const float* __restrict__ wp3,
    const float* __restrict__ wo1, const float* __restrict__ wo2, const float* __restrict__ wo3,
    _Float16* __restrict__ dfh, _Float16* __restrict__ pfh,
    _Float16* __restrict__ wd1t, _Float16* __restrict__ wd2t, _Float16* __restrict__ wd3t,
    _Float16* __restrict__ wp1t, _Float16* __restrict__ wp2t, _Float16* __restrict__ wp3t,
    _Float16* __restrict__ wo1t, _Float16* __restrict__ wo2t, _Float16* __restrict__ wo3t,
    const float* __restrict__ Ac, const float* __restrict__ Ap,
    const float* __restrict__ Xc, const float* __restrict__ Xp,
    _Float16* __restrict__ Ahc, _Float16* __restrict__ Ahp,
    _Float16* __restrict__ Xtc, _Float16* __restrict__ Xtp,
    _Float16* __restrict__ Xtca, _Float16* __restrict__ Xtpa)
{
    int j = blockIdx.x * 256 + threadIdx.x;
    if (j < 16896) {
        int L = j / 5632, rem = j % 5632;
        int dr = rem >> 9, r2 = rem & 511, ln = r2 >> 3, i = r2 & 7;
        int dc = 8 * (ln >> 4) + i - (ln & 15);
        float v = (dc >= 0 && dc < 11) ? K_cnn[L * 121 + dr * 11 + dc] : 0.f;
        wtab[j] = (_Float16)v;
        return;
    }
    j -= 16896;
    if (j < NW * 80) {
        int w = j / 80, h = j - w * 80;
        float v = (h >= 13 && h < 77) ? ew[w * 64 + (h - 13)] : 0.f;
        ehp[j] = (_Float16)v;
        return;
    }
    j -= NW * 80;
    if (j < 2048000) { dfh[j] = (_Float16)df[j]; return; }
    j -= 2048000;
    if (j < 1536000) { pfh[j] = (_Float16)pf[j]; return; }
    j -= 1536000;
    if (j < 131072) { int n = j >> 10, k = j & 1023; wd1t[j] = (_Float16)wd1[k * 128 + n]; return; }
    j -= 131072;
    if (j < 8192)  { int n = j >> 7, k = j & 127; wd2t[j] = (_Float16)wd2[k * 64 + n]; return; }
    j -= 8192;
    if (j < 4096)  { int n = j >> 6, k = j & 63; wd3t[j] = (_Float16)wd3[k * 64 + n]; return; }
    j -= 4096;
    if (j < 131072) { int n = j >> 10, k = j & 1023; wp1t[j] = (_Float16)wp1[k * 128 + n]; return; }
    j -= 131072;
    if (j < 8192)  { int n = j >> 7, k = j & 127; wp2t[j] = (_Float16)wp2[k * 64 + n]; return; }
    j -= 8192;
    if (j < 4096)  { int n = j >> 6, k = j & 63; wp3t[j] = (_Float16)wp3[k * 64 + n]; return; }
    j -= 4096;
    if (j < 98304) { int n = j / 384, k = j - n * 384; wo1t[j] = (_Float16)wo1[k * 256 + n]; return; }
    j -= 98304;
    if (j < 65536) { int n = j >> 8, k = j & 255; wo2t[j] = (_Float16)wo2[k * 256 + n]; return; }
    j -= 65536;
    if (j < 65536) { int n = j >> 8, k = j & 255; wo3t[j] = (_Float16)wo3[k * 256 + n]; return; }
    j -= 65536;
    if (j < KPC * KPC) {
        int r = j >> 11, c = j & (KPC - 1);
        Ahc[j] = (_Float16)((r < NC && c < NC) ? Ac[(size_t)r * NC + c] : 0.f);
        return;
    }
    j -= KPC * KPC;
    if (j < KPP * KPP) {
        int r = j / KPP, c = j - r * KPP;
        Ahp[j] = (_Float16)((r < NP && c < NP) ? Ap[(size_t)r * NP + c] : 0.f);
        return;
    }
    j -= KPP * KPP;
    if (j < 64 * KPC) {
        int c = j >> 11, r = j & (KPC - 1);
        Xtc[j] = (_Float16)((r < NC) ? Xc[(size_t)r * 64 + c] : 0.f);
        return;
    }
    j -= 64 * KPC;
    if (j < 64 * KPP) {
        int c = j / KPP, r = j - c * KPP;
        Xtp[j] = (_Float16)((r < NP) ? Xp[(size_t)r * 64 + c] : 0.f);
        return;
    }
    j -= 64 * KPP;
    if (j < 64 * KPC) { Xtca[j] = (_Float16)0.f; return; }
    j -= 64 * KPC;
    if (j < 64 * KPP) { Xtpa[j] = (_Float16)0.f; }
}
#define PREP_TOTAL (16896 + NW * 80 + 2048000 + 1536000 + 131072 + 8192 + 4096 + 131072 + 8192 + 4096 + 98304 + 65536 + 65536 + KPC * KPC + KPP * KPP + 64 * KPC + 64 * KPP + 64 * KPC + 64 * KPP)

// =============== MEGA kernel: GNN (blocks 0..NC-1) + CNN (rest) ===============
// GNN: 256-thread version; LDS fp16 for hs/Ws/adjS so union fits CNN's 31744 B.
// CNN: banded-MFMA 3-layer conv, unchanged from round 14.
__global__ __launch_bounds__(256) void mega_kernel(
    // CNN
    const int* __restrict__ proteins, const _Float16* __restrict__ ehp,
    const half8_t* __restrict__ wtab, const float* __restrict__ b_cnn,
    float* __restrict__ prot_part,
    // GNN
    const int* __restrict__ compounds, const float* __restrict__ adjacencies,
    const float* __restrict__ embed_fp, const float* __restrict__ W_gnn,
    const float* __restrict__ b_gnn, _Float16* __restrict__ comp_h)
{
    __shared__ union SM {
        struct { half8_t bufA8[62 * 16]; half8_t bufB8[62 * 16]; } c;         // 31744 B
        struct { float xs[40][68]; _Float16 hs[40][72];
                 _Float16 Ws[64][64]; _Float16 adjS[40][40]; float bS[64]; } g; // 28288 B
    } sm;
    const int bx = blockIdx.x;
    const int tid = threadIdx.x;

    if (bx < NC) {
        // ---------------- GNN branch ----------------
        auto& G = sm.g;
        const int n = bx;
        for (int j = tid; j < 40 * 64; j += 256) {
            int r = j >> 6, c = j & 63;
            G.xs[r][c] = embed_fp[(size_t)compounds[n * NA + r] * 64 + c];
        }
        for (int j = tid; j < 1600; j += 256)
            G.adjS[j / 40][j % 40] = (_Float16)adjacencies[(size_t)n * 1600 + j];

        const int a0 = tid >> 3, cb = (tid & 7) * 8;
        const bool hasB = tid < 64;
        const int a1 = hasB ? (32 + (tid >> 3)) : 0;

        for (int l = 0; l < 3; ++l) {
            __syncthreads();
            for (int j = tid; j < 4096; j += 256) G.Ws[j >> 6][j & 63] = (_Float16)W_gnn[l * 4096 + j];
            if (tid < 64) G.bS[tid] = b_gnn[l * 64 + tid];
            __syncthreads();
            float accA[8], accB[8];
            #pragma unroll
            for (int j = 0; j < 8; ++j) { accA[j] = G.bS[cb + j]; accB[j] = accA[j]; }
            for (int d = 0; d < 64; ++d) {
                float xA = G.xs[a0][d];
                float xB = hasB ? G.xs[a1][d] : 0.f;
                #pragma unroll
                for (int j = 0; j < 8; ++j) {
                    float w = (float)G.Ws[d][cb + j];
                    accA[j] += xA * w;
                    accB[j] += xB * w;
                }
            }
            #pragma unroll
            for (int j = 0; j < 8; ++j) {
                G.hs[a0][cb + j] = (_Float16)fmaxf(accA[j], 0.f);
                if (hasB) G.hs[a1][cb + j] = (_Float16)fmaxf(accB[j], 0.f);
            }
            __syncthreads();
            float xA[8], xB[8];
            #pragma unroll
            for (int j = 0; j < 8; ++j) { xA[j] = G.xs[a0][cb + j]; xB[j] = hasB ? G.xs[a1][cb + j] : 0.f; }
            for (int b = 0; b < NA; ++b) {
                float adA = (float)G.adjS[a0][b];
                float adB = (float)G.adjS[a1][b];
                #pragma unroll
                for (int j = 0; j < 8; ++j) {
                    float h = (float)G.hs[b][cb + j];
                    xA[j] += adA * h;
                    xB[j] += adB * h;
                }
            }
            #pragma unroll
            for (int j = 0; j < 8; ++j) {
                G.xs[a0][cb + j] = xA[j];
                if (hasB) G.xs[a1][cb + j] = xB[j];
            }
        }
        __syncthreads();
        if (tid < 64) {
            float s = 0.f;
            for (int r = 0; r < NA; ++r) s += G.xs[r][tid];
            comp_h[n * 64 + tid] = (_Float16)(s * (1.0f / 40.0f));
        }
        return;
    }

    // ---------------- CNN branch ----------------
    _Float16* bufA = (_Float16*)sm.c.bufA8;
    _Float16* bufB = (_Float16*)sm.c.bufB8;
    half8_t* bufA8 = sm.c.bufA8;
    half8_t* bufB8 = sm.c.bufB8;

    const int cb_ = bx - NC;
    const int tile = cb_ & 15, p = cb_ >> 4;
    const int t0 = tile * 32;
    const int lane = tid & 63, wid = tid >> 6;
    const int c0 = wid * 16;
    const int m = lane & 15, g = lane >> 4;

    half8_t z = {};
    for (int e = tid; e < 62 * 9; e += 256) {
        int i = e / 9, a = 1 + (e - 9 * i);
        int gr = t0 - 15 + i;
        half8_t v = z;
        if (gr >= 0 && gr < LP)
            v = *(const half8_t*)&ehp[(size_t)proteins[p * LP + gr] * 80 + 8 * a];
        *(half8_t*)&bufA[i * 128 + (((a & 8) | ((a ^ i) & 7)) << 3)] = v;
    }
    // zero read-but-never-stored blocks: bufA blk10; bufB blk1, blk9, blk10
    for (int e = tid; e < 62 * 4; e += 256) {
        int i = e >> 2, w = e & 3;
        if (w == 0)      bufA8[i * 16 + (8 | ((10 ^ i) & 7))] = z;
        else if (w == 1) bufB8[i * 16 + ((1 ^ i) & 7)] = z;
        else {
            int blk = 7 + w;
            bufB8[i * 16 + ((blk & 8) | ((blk ^ i) & 7))] = z;
        }
    }

    half8_t wf[11];
    auto load_wf = [&](int L) {
        #pragma unroll
        for (int dr = 0; dr < 11; ++dr) wf[dr] = wtab[L * 11 * 64 + dr * 64 + lane];
    };
    auto conv_tile = [&](const _Float16* src, int r0, float bias) -> f32x4 {
        f32x4 acc = {bias, bias, bias, bias};
        const int B0 = (c0 + 8) >> 3;
        #pragma unroll
        for (int dr = 0; dr < 11; ++dr) {
            int R = r0 - 5 + dr + m;
            int b = B0 + g;
            half8_t a = *(const half8_t*)&src[R * 128 + (((b & 8) | ((b ^ R) & 7)) << 3)];
            acc = __builtin_amdgcn_mfma_f32_16x16x32_f16(a, wf[dr], acc, 0, 0, 0);
        }
        return acc;
    };
    auto store_tile = [&](_Float16* dst, int r0, f32x4 acc) {
        int pc = c0 + 13 + m;
        #pragma unroll
        for (int j = 0; j < 4; ++j) {
            int row = r0 + 4 * g + j;
            int og = t0 - 15 + row;
            float v = fmaxf(acc[j], 0.f);
            dst[swz_off(row, pc)] = (_Float16)((og >= 0 && og < LP) ? v : 0.f);
        }
    };

    load_wf(0);
    __syncthreads();
    {
        float b0 = b_cnn[0];
        const int r0s[4] = {5, 21, 37, 41};
        #pragma unroll
        for (int k = 0; k < 4; ++k) store_tile(bufB, r0s[k], conv_tile(bufA, r0s[k], b0));
    }
    __syncthreads();
    load_wf(1);
    {
        float b1 = b_cnn[1];
        const int r0s[3] = {10, 26, 36};
        #pragma unroll
        for (int k = 0; k < 3; ++k) store_tile(bufA, r0s[k], conv_tile(bufB, r0s[k], b1));
    }
    __syncthreads();
    load_wf(2);
    {
        float b2 = b_cnn[2];
        float cs = 0.f;
        const int r0s[2] = {15, 31};
        #pragma unroll
        for (int k = 0; k < 2; ++k) {
            f32x4 acc = conv_tile(bufA, r0s[k], b2);
            #pragma unroll
            for (int j = 0; j < 4; ++j) cs += fmaxf(acc[j], 0.f);
        }
        cs += __shfl_xor(cs, 16, 64);
        cs += __shfl_xor(cs, 32, 64);
        if (lane < 16)
            prot_part[((size_t)p * 16 + tile) * 64 + c0 + lane] = cs;
    }
}

__global__ void cnn_reduce(const float* __restrict__ prot_part, _Float16* __restrict__ prot_h)
{
    const int p = blockIdx.x, c = threadIdx.x;
    float s = 0.f;
    for (int t = 0; t < 16; ++t) s += prot_part[((size_t)p * 16 + t) * 64 + c];
    prot_h[p * 64 + c] = (_Float16)(s * (1.0f / 512.0f));
}

// ======== GCN: MFMA split-K GEMM part = A@X (drug z=0, protein z=1) ========
__global__ __launch_bounds__(256) void spk_mfma_dual(
    const _Float16* __restrict__ Ah0, const _Float16* __restrict__ Xt0, float* __restrict__ P0, int M0, int Kp0,
    const _Float16* __restrict__ Ah1, const _Float16* __restrict__ Xt1, float* __restrict__ P1, int M1, int Kp1,
    int nx1)
{
    const _Float16* Ah; const _Float16* Xt; float* part; int M, Kp;
    if (blockIdx.z == 0) { Ah = Ah0; Xt = Xt0; part = P0; M = M0; Kp = Kp0; }
    else { if ((int)blockIdx.x >= nx1) return; Ah = Ah1; Xt = Xt1; part = P1; M = M1; Kp = Kp1; }

    const int tid = threadIdx.x, wid = tid >> 6, lane = tid & 63;
    const int m = lane & 15, g = lane >> 4;
    const int row0 = blockIdx.x * 64 + wid * 16;
    const int chunk = Kp >> 3, k0 = blockIdx.y * chunk;
    const _Float16* Apr = Ah + (size_t)(row0 + m) * Kp + 8 * g;
    f32x4 acc[4] = {};
    for (int kb = k0; kb < k0 + chunk; kb += 32) {
        half8_t af = *(const half8_t*)&Apr[kb];
        #pragma unroll
        for (int t = 0; t < 4; ++t) {
            half8_t bf = *(const half8_t*)&Xt[(size_t)(t * 16 + m) * Kp + kb + 8 * g];
            acc[t] = __builtin_amdgcn_mfma_f32_16x16x32_f16(af, bf, acc[t], 0, 0, 0);
        }
    }
    const int s = blockIdx.y;
    #pragma unroll
    for (int t = 0; t < 4; ++t)
        #pragma unroll
        for (int j = 0; j < 4; ++j) {
            int row = row0 + 4 * g + j;
            if (row < M) part[((size_t)s * M + row) * 64 + t * 16 + m] = acc[t][j];
        }
}

// epilogue: sum 8 partials, @W + bias + relu; nullable H / XtN outputs
__global__ __launch_bounds__(256) void gcn_epi_dual(
    const float* __restrict__ P0, int M0, const float* __restrict__ W0, const float* __restrict__ b0,
    _Float16* __restrict__ H0, _Float16* __restrict__ XtN0, int Kp0,
    const float* __restrict__ P1, int M1, const float* __restrict__ W1, const float* __restrict__ b1,
    _Float16* __restrict__ H1, _Float16* __restrict__ XtN1, int Kp1, int nx1)
{
    const float* part; const float* W; const float* bias; _Float16* H; _Float16* XtN; int M, Kp;
    if (blockIdx.z == 0) { part = P0; W = W0; bias = b0; H = H0; XtN = XtN0; M = M0; Kp = Kp0; }
    else { if ((int)blockIdx.x >= nx1) return; part = P1; W = W1; bias = b1; H = H1; XtN = XtN1; M = M1; Kp = Kp1; }

    __shared__ float Ys[64][68];
    __shared__ float Ws[64][64];
    const int rb = blockIdx.x * 64;
    const int tid = threadIdx.x;
    for (int j = tid; j < 4096; j += 256) Ws[j >> 6][j & 63] = W[j];
    for (int j = tid; j < 4096; j += 256) {
        int r = j >> 6, c = j & 63;
        float sum = 0.f;
        if (rb + r < M)
            for (int t = 0; t < 8; ++t) sum += part[((size_t)t * M + rb + r) * 64 + c];
        Ys[r][c] = sum;
    }
    __syncthreads();
    const int tx = tid & 15, ty = tid >> 4;
    float acc[4][4];
    #pragma unroll
    for (int i = 0; i < 4; ++i)
        #pragma unroll
        for (int j = 0; j < 4; ++j) acc[i][j] = bias[tx * 4 + j];
    for (int d = 0; d < 64; ++d) {
        float a0 = Ys[ty * 4 + 0][d], a1 = Ys[ty * 4 + 1][d];
        float a2 = Ys[ty * 4 + 2][d], a3 = Ys[ty * 4 + 3][d];
        float4 w4 = *(const float4*)&Ws[d][tx * 4];
        acc[0][0] += a0 * w4.x; acc[0][1] += a0 * w4.y; acc[0][2] += a0 * w4.z; acc[0][3] += a0 * w4.w;
        acc[1][0] += a1 * w4.x; acc[1][1] += a1 * w4.y; acc[1][2] += a1 * w4.z; acc[1][3] += a1 * w4.w;
        acc[2][0] += a2 * w4.x; acc[2][1] += a2 * w4.y; acc[2][2] += a2 * w4.z; acc[2][3] += a2 * w4.w;
        acc[3][0] += a3 * w4.x; acc[3][1] += a3 * w4.y; acc[3][2] += a3 * w4.z; acc[3][3] += a3 * w4.w;
    }
    #pragma unroll
    for (int i = 0; i < 4; ++i) {
        int row = rb + ty * 4 + i;
        if (row < M) {
            #pragma unroll
            for (int j = 0; j < 4; ++j) {
                int col = tx * 4 + j;
                float v = fmaxf(acc[i][j], 0.f);
                if (H)   H[(size_t)row * 64 + col] = (_Float16)v;
                if (XtN) XtN[(size_t)col * Kp + row] = (_Float16)v;
            }
        }
    }
}

// ======== MFMA MLP GEMM (dual, col-split) ========
template<int NT, bool GATHER>
__global__ __launch_bounds__(256) void mfma_mlp(
    const _Float16* __restrict__ A0, const int* __restrict__ idx0,
    const _Float16* __restrict__ Bt0, const float* __restrict__ bias0, _Float16* __restrict__ C0,
    const _Float16* __restrict__ A1, const int* __restrict__ idx1,
    const _Float16* __restrict__ Bt1, const float* __restrict__ bias1, _Float16* __restrict__ C1,
    int K, int N)
{
    const _Float16* A; const int* idx; const _Float16* Bt; const float* bias; _Float16* C;
    if (blockIdx.z == 0) { A = A0; idx = idx0; Bt = Bt0; bias = bias0; C = C0; }
    else                 { A = A1; idx = idx1; Bt = Bt1; bias = bias1; C = C1; }
    const int tid = threadIdx.x, wid = tid >> 6, lane = tid & 63;
    const int m = lane & 15, g = lane >> 4;
    const int row0 = blockIdx.x * 64 + wid * 16;
    const int col0 = blockIdx.y * (NT * 16);
    size_t arow = GATHER ? (size_t)idx[row0 + m] : (size_t)(row0 + m);
    const _Float16* Ap = A + arow * (size_t)K + 8 * g;
    f32x4 acc[NT] = {};
    for (int kb = 0; kb < K; kb += 32) {
        half8_t af = *(const half8_t*)&Ap[kb];
        #pragma unroll
        for (int t = 0; t < NT; ++t) {
            half8_t bf = *(const half8_t*)&Bt[(size_t)(col0 + t * 16 + m) * K + kb + 8 * g];
            acc[t] = __builtin_amdgcn_mfma_f32_16x16x32_f16(af, bf, acc[t], 0, 0, 0);
        }
    }
    __shared__ float cb[4][16][17];
    const int rr = lane >> 2, c4 = (lane & 3) * 4;
    #pragma unroll
    for (int t = 0; t < NT; ++t) {
        #pragma unroll
        for (int j = 0; j < 4; ++j) cb[wid][4 * g + j][m] = acc[t][j];
        half4_t h;
        #pragma unroll
        for (int j = 0; j < 4; ++j)
            h[j] = (_Float16)fmaxf(cb[wid][rr][c4 + j] + bias[col0 + t * 16 + c4 + j], 0.f);
        *(half4_t*)&C[(size_t)(row0 + rr) * N + col0 + t * 16 + c4] = h;
    }
}

// head GEMM1 with fused concat
__global__ __launch_bounds__(256) void mfma_head1(
    const int* __restrict__ idx_c, const int* __restrict__ idx_p,
    const _Float16* __restrict__ ci, const _Float16* __restrict__ xc, const _Float16* __restrict__ fd,
    const _Float16* __restrict__ pi, const _Float16* __restrict__ xp, const _Float16* __restrict__ fp,
    const _Float16* __restrict__ Bt, const float* __restrict__ bias, _Float16* __restrict__ C)
{
    const int tid = threadIdx.x, wid = tid >> 6, lane = tid & 63;
    const int m = lane & 15, g = lane >> 4;
    const int row0 = blockIdx.x * 64 + wid * 16;
    const int col0 = blockIdx.y * 32;
    int ic = idx_c[row0 + m], ip = idx_p[row0 + m];
    const _Float16* segs[6] = {
        ci + (size_t)ic * 64 + 8 * g,  xc + (size_t)ic * 64 + 8 * g,
        fd + (size_t)(row0 + m) * 64 + 8 * g,
        pi + (size_t)ip * 64 + 8 * g,  xp + (size_t)ip * 64 + 8 * g,
        fp + (size_t)(row0 + m) * 64 + 8 * g };
    f32x4 acc[2] = {};
    #pragma unroll
    for (int kb = 0; kb < 384; kb += 32) {
        half8_t af = *(const half8_t*)&segs[kb / 64][kb & 63];
        #pragma unroll
        for (int t = 0; t < 2; ++t) {
            half8_t bf = *(const half8_t*)&Bt[(size_t)(col0 + t * 16 + m) * 384 + kb + 8 * g];
            acc[t] = __builtin_amdgcn_mfma_f32_16x16x32_f16(af, bf, acc[t], 0, 0, 0);
        }
    }
    __shared__ float cb[4][16][17];
    const int rr = lane >> 2, c4 = (lane & 3) * 4;
    #pragma unroll
    for (int t = 0; t < 2; ++t) {
        #pragma unroll
        for (int j = 0; j < 4; ++j) cb[wid][4 * g + j][m] = acc[t][j];
        half4_t h;
        #pragma unroll
        for (int j = 0; j < 4; ++j)
            h[j] = (_Float16)fmaxf(cb[wid][rr][c4 + j] + bias[col0 + t * 16 + c4 + j], 0.f);
        *(half4_t*)&C[(size_t)(row0 + rr) * 256 + col0 + t * 16 + c4] = h;
    }
}

// head GEMM3 + fused final 256x2 matmul + sigmoid
__global__ __launch_bounds__(256) void mfma_head3(
    const _Float16* __restrict__ A, const _Float16* __restrict__ Bt,
    const float* __restrict__ bias, const float* __restrict__ Wi, const float* __restrict__ bi,
    float* __restrict__ out)
{
    const int tid = threadIdx.x, wid = tid >> 6, lane = tid & 63;
    const int m = lane & 15, g = lane >> 4;
    const int row0 = blockIdx.x * 64 + wid * 16;
    const _Float16* Ap = A + (size_t)(row0 + m) * 256 + 8 * g;
    f32x4 acc[16] = {};
    for (int kb = 0; kb < 256; kb += 32) {
        half8_t af = *(const half8_t*)&Ap[kb];
        #pragma unroll
        for (int t = 0; t < 16; ++t) {
            half8_t bf = *(const half8_t*)&Bt[(size_t)(t * 16 + m) * 256 + kb + 8 * g];
            acc[t] = __builtin_amdgcn_mfma_f32_16x16x32_f16(af, bf, acc[t], 0, 0, 0);
        }
    }
    float p0[4] = {}, p1[4] = {};
    #pragma unroll
    for (int t = 0; t < 16; ++t) {
        float w0 = Wi[(t * 16 + m) * 2], w1 = Wi[(t * 16 + m) * 2 + 1];
        float bc = bias[t * 16 + m];
        #pragma unroll
        for (int j = 0; j < 4; ++j) {
            float v = fmaxf(acc[t][j] + bc, 0.f);
            p0[j] += v * w0; p1[j] += v * w1;
        }
    }
    #pragma unroll
    for (int d = 1; d < 16; d <<= 1) {
        #pragma unroll
        for (int j = 0; j < 4; ++j) {
            p0[j] += __shfl_xor(p0[j], d, 64);
            p1[j] += __shfl_xor(p1[j], d, 64);
        }
    }
    if (m == 0) {
        float B0 = bi[0], B1 = bi[1];
        #pragma unroll
        for (int j = 0; j < 4; ++j) {
            int r = row0 + 4 * g + j;
            out[r * 2 + 0] = 1.f / (1.f + expf(-(p0[j] + B0)));
            out[r * 2 + 1] = 1.f / (1.f + expf(-(p1[j] + B1)));
        }
    }
}

// ======================= launch =======================
extern "C" void kernel_launch(void* const* d_in, const int* in_sizes, int n_in,
                              void* d_out, int out_size, void* d_ws, size_t ws_size,
                              hipStream_t stream)
{
    const int*   idx_c        = (const int*)  d_in[0];
    const int*   idx_p        = (const int*)  d_in[1];
    const int*   compounds    = (const int*)  d_in[2];
    const int*   proteins     = (const int*)  d_in[3];
    const float* adjacencies  = (const float*)d_in[4];
    const float* A_c          = (const float*)d_in[5];
    const float* A_p          = (const float*)d_in[6];
    const float* embed_fp     = (const float*)d_in[7];
    const float* embed_word   = (const float*)d_in[8];
    const float* Xs_c         = (const float*)d_in[9];
    const float* Xs_p         = (const float*)d_in[10];
    const float* drug_feat    = (const float*)d_in[11];
    const float* protein_feat = (const float*)d_in[12];
    const float* W_gnn        = (const float*)d_in[13];
    const float* b_gnn        = (const float*)d_in[14];
    const float* K_cnn        = (const float*)d_in[15];
    const float* b_cnn        = (const float*)d_in[16];
    const float* W_gcn_d      = (const float*)d_in[17];
    const float* b_gcn_d      = (const float*)d_in[18];
    const float* W_gcn_p      = (const float*)d_in[19];
    const float* b_gcn_p      = (const float*)d_in[20];
    const float* Wd1 = (const float*)d_in[21]; const float* bd1 = (const float*)d_in[22];
    const float* Wd2 = (const float*)d_in[23]; const float* bd2 = (const float*)d_in[24];
    const float* Wd3 = (const float*)d_in[25]; const float* bd3 = (const float*)d_in[26];
    const float* Wp1 = (const float*)d_in[27]; const float* bp1 = (const float*)d_in[28];
    const float* Wp2 = (const float*)d_in[29]; const float* bp2 = (const float*)d_in[30];
    const float* Wp3 = (const float*)d_in[31]; const float* bp3 = (const float*)d_in[32];
    const float* Wo1 = (const float*)d_in[33]; const float* bo1 = (const float*)d_in[34];
    const float* Wo2 = (const float*)d_in[35]; const float* bo2 = (const float*)d_in[36];
    const float* Wo3 = (const float*)d_in[37]; const float* bo3 = (const float*)d_in[38];
    const float* W_int = (const float*)d_in[39]; const float* b_int = (const float*)d_in[40];

    float* ws = (float*)d_ws;
    float* prot_part = ws; ws += NP * 16 * 64;
    float* wtab_g    = ws; ws += 8448;
    float* ehp_g     = ws; ws += NW * 40;
    float* part_c    = ws; ws += 8 * NC * 64;
    float* part_p    = ws; ws += 8 * NP * 64;
    _Float16* Ah_c  = (_Float16*)ws; ws += KPC * KPC / 2;
    _Float16* Ah_p  = (_Float16*)ws; ws += KPP * KPP / 2;
    _Float16* Xt_c  = (_Float16*)ws; ws += 32 * KPC;
    _Float16* Xt_p  = (_Float16*)ws; ws += 32 * KPP;
    _Float16* Xt_ca = (_Float16*)ws; ws += 32 * KPC;
    _Float16* Xt_pa = (_Float16*)ws; ws += 32 * KPP;
    _Float16* comp_h  = (_Float16*)ws; ws += NC * 32;
    _Float16* prot_h  = (_Float16*)ws; ws += NP * 32;
    _Float16* Xcb_h   = (_Float16*)ws; ws += NC * 32;
    _Float16* Xpb_h   = (_Float16*)ws; ws += NP * 32;
    _Float16* drug_h  = (_Float16*)ws; ws += NC * 512;
    _Float16* protf_h = (_Float16*)ws; ws += NP * 512;
    _Float16* wd1t = (_Float16*)ws; ws += 65536;
    _Float16* wd2t = (_Float16*)ws; ws += 4096;
    _Float16* wd3t = (_Float16*)ws; ws += 2048;
    _Float16* wp1t = (_Float16*)ws; ws += 65536;
    _Float16* wp2t = (_Float16*)ws; ws += 4096;
    _Float16* wp3t = (_Float16*)ws; ws += 2048;
    _Float16* wo1t = (_Float16*)ws; ws += 49152;
    _Float16* wo2t = (_Float16*)ws; ws += 32768;
    _Float16* wo3t = (_Float16*)ws; ws += 32768;
    _Float16* fd1h = (_Float16*)ws; ws += BSZ * 64;
    _Float16* fd2h = (_Float16*)ws; ws += BSZ * 32;
    _Float16* fd3h = (_Float16*)ws; ws += BSZ * 32;
    _Float16* fp1h = (_Float16*)ws; ws += BSZ * 64;
    _Float16* fp2h = (_Float16*)ws; ws += BSZ * 32;
    _Float16* fp3h = (_Float16*)ws; ws += BSZ * 32;
    _Float16* h1h  = (_Float16*)ws; ws += BSZ * 128;
    _Float16* h2h  = (_Float16*)ws; ws += BSZ * 128;
    (void)ws_size; (void)in_sizes; (void)n_in; (void)out_size;

    // one-time prep (single kernel)
    prep_all<<<(PREP_TOTAL + 255) / 256, 256, 0, stream>>>(
        K_cnn, (_Float16*)wtab_g, embed_word, (_Float16*)ehp_g,
        drug_feat, protein_feat, Wd1, Wd2, Wd3, Wp1, Wp2, Wp3, Wo1, Wo2, Wo3,
        drug_h, protf_h, wd1t, wd2t, wd3t, wp1t, wp2t, wp3t, wo1t, wo2t, wo3t,
        A_c, A_p, Xs_c, Xs_p, Ah_c, Ah_p, Xt_c, Xt_p, Xt_ca, Xt_pa);
    // GNN (blocks 0..NC-1) + CNN (blocks NC..NC+16*NP-1) in one dispatch
    mega_kernel<<<NC + 16 * NP, 256, 0, stream>>>(
        proteins, (const _Float16*)ehp_g, (const half8_t*)wtab_g, b_cnn, prot_part,
        compounds, adjacencies, embed_fp, W_gnn, b_gnn, comp_h);
    cnn_reduce<<<NP, 64, 0, stream>>>(prot_part, prot_h);
    // GCN drug+protein (MFMA)
    spk_mfma_dual<<<dim3(32, 8, 2), 256, 0, stream>>>(
        Ah_c, Xt_c, part_c, NC, KPC, Ah_p, Xt_p, part_p, NP, KPP, 24);
    gcn_epi_dual<<<dim3(32, 1, 2), 256, 0, stream>>>(
        part_c, NC, W_gcn_d, b_gcn_d, nullptr, Xt_ca, KPC,
        part_p, NP, W_gcn_p, b_gcn_p, nullptr, Xt_pa, KPP, 24);
    spk_mfma_dual<<<dim3(32, 8, 2), 256, 0, stream>>>(
        Ah_c, Xt_ca, part_c, NC, KPC, Ah_p, Xt_pa, part_p, NP, KPP, 24);
    gcn_epi_dual<<<dim3(32, 1, 2), 256, 0, stream>>>(
        part_c, NC, W_gcn_d + 4096, b_gcn_d + 64, Xcb_h, nullptr, KPC,
        part_p, NP, W_gcn_p + 4096, b_gcn_p + 64, Xpb_h, nullptr, KPP, 24);
    // annotation MLPs (MFMA, dual, col-split)
    mfma_mlp<2, true ><<<dim3(64, 4, 2), 256, 0, stream>>>(
        drug_h, idx_c, wd1t, bd1, fd1h, protf_h, idx_p, wp1t, bp1, fp1h, 1024, 128);
    mfma_mlp<1, false><<<dim3(64, 4, 2), 256, 0, stream>>>(
        fd1h, nullptr, wd2t, bd2, fd2h, fp1h, nullptr, wp2t, bp2, fp2h, 128, 64);
    mfma_mlp<1, false><<<dim3(64, 4, 2), 256, 0, stream>>>(
        fd2h, nullptr, wd3t, bd3, fd3h, fp2h, nullptr, wp3t, bp3, fp3h, 64, 64);
    // head
    mfma_head1<<<dim3(64, 8), 256, 0, stream>>>(idx_c, idx_p, comp_h, Xcb_h, fd3h,
                                                prot_h, Xpb_h, fp3h, wo1t, bo1, h1h);
    mfma_mlp<2, false><<<dim3(64, 8, 1), 256, 0, stream>>>(
        h1h, nullptr, wo2t, bo2, h2h, h1h, nullptr, wo2t, bo2, h2h, 256, 256);
    mfma_head3<<<64, 256, 0, stream>>>(h2h, wo3t, bo3, W_int, b_int, (float*)d_out);
}

// Round 16
// 349.041 us; speedup vs baseline: 1.6960x; 1.2153x over previous
//
#include <hip/hip_runtime.h>
#include <math.h>

#define NC 2000
#define NP 1500
#define NA 40
#define LP 512
#define BSZ 4096
#define NW 8000
#define KPC 2048   // padded K for drug GCN
#define KPP 1536   // padded K for protein GCN

typedef _Float16 half8_t __attribute__((ext_vector_type(8)));
typedef _Float16 half4_t __attribute__((ext_vector_type(4)));
typedef float f32x4 __attribute__((ext_vector_type(4)));

__device__ __forceinline__ int swz_off(int row, int half_col)
{
    int b = half_col >> 3;
    return row * 128 + (((b & 8) | ((b ^ row) & 7)) << 3) + (half_col & 7);
}

// =============== one-time prep: all fp16 tables/copies in one kernel ===============
__global__ void prep_all(
    const float* __restrict__ K_cnn, _Float16* __restrict__ wtab,
    const float* __restrict__ ew, _Float16* __restrict__ ehp,
    const float* __restrict__ df, const float* __restrict__ pf,
    const float* __restrict__ wd1, const float* __restrict__ wd2, const float* __restrict__ wd3,
    const float* __restrict__ wp1, const float* __restrict__ wp2, const float* __restrict__ wp3,
    const float* __restrict__ wo1, const float* __restrict__ wo2, const float* __restrict__ wo3,
    _Float16* __restrict__ dfh, _Float16* __restrict__ pfh,
    _Float16* __restrict__ wd1t, _Float16* __restrict__ wd2t, _Float16* __restrict__ wd3t,
    _Float16* __restrict__ wp1t, _Float16* __restrict__ wp2t, _Float16* __restrict__ wp3t,
    _Float16* __restrict__ wo1t, _Float16* __restrict__ wo2t, _Float16* __restrict__ wo3t,
    const float* __restrict__ wgnn, _Float16* __restrict__ wgt,
    const float* __restrict__ Ac, const float* __restrict__ Ap,
    const float* __restrict__ Xc, const float* __restrict__ Xp,
    _Float16* __restrict__ Ahc, _Float16* __restrict__ Ahp,
    _Float16* __restrict__ Xtc, _Float16* __restrict__ Xtp,
    _Float16* __restrict__ Xtca, _Float16* __restrict__ Xtpa)
{
    int j = blockIdx.x * 256 + threadIdx.x;
    if (j < 16896) {
        int L = j / 5632, rem = j % 5632;
        int dr = rem >> 9, r2 = rem & 511, ln = r2 >> 3, i = r2 & 7;
        int dc = 8 * (ln >> 4) + i - (ln & 15);
        float v = (dc >= 0 && dc < 11) ? K_cnn[L * 121 + dr * 11 + dc] : 0.f;
        wtab[j] = (_Float16)v;
        return;
    }
    j -= 16896;
    if (j < NW * 80) {
        int w = j / 80, h = j - w * 80;
        float v = (h >= 13 && h < 77) ? ew[w * 64 + (h - 13)] : 0.f;
        ehp[j] = (_Float16)v;
        return;
    }
    j -= NW * 80;
    if (j < 2048000) { dfh[j] = (_Float16)df[j]; return; }
    j -= 2048000;
    if (j < 1536000) { pfh[j] = (_Float16)pf[j]; return; }
    j -= 1536000;
    if (j < 131072) { int n = j >> 10, k = j & 1023; wd1t[j] = (_Float16)wd1[k * 128 + n]; return; }
    j -= 131072;
    if (j < 8192)  { int n = j >> 7, k = j & 127; wd2t[j] = (_Float16)wd2[k * 64 + n]; return; }
    j -= 8192;
    if (j < 4096)  { int n = j >> 6, k = j & 63; wd3t[j] = (_Float16)wd3[k * 64 + n]; return; }
    j -= 4096;
    if (j < 131072) { int n = j >> 10, k = j & 1023; wp1t[j] = (_Float16)wp1[k * 128 + n]; return; }
    j -= 131072;
    if (j < 8192)  { int n = j >> 7, k = j & 127; wp2t[j] = (_Float16)wp2[k * 64 + n]; return; }
    j -= 8192;
    if (j < 4096)  { int n = j >> 6, k = j & 63; wp3t[j] = (_Float16)wp3[k * 64 + n]; return; }
    j -= 4096;
    if (j < 98304) { int n = j / 384, k = j - n * 384; wo1t[j] = (_Float16)wo1[k * 256 + n]; return; }
    j -= 98304;
    if (j < 65536) { int n = j >> 8, k = j & 255; wo2t[j] = (_Float16)wo2[k * 256 + n]; return; }
    j -= 65536;
    if (j < 65536) { int n = j >> 8, k = j & 255; wo3t[j] = (_Float16)wo3[k * 256 + n]; return; }
    j -= 65536;
    if (j < 12288) { int l = j >> 12, rem = j & 4095, nn = rem >> 6, k = rem & 63;
                     wgt[j] = (_Float16)wgnn[l * 4096 + k * 64 + nn]; return; }
    j -= 12288;
    if (j < KPC * KPC) {
        int r = j >> 11, c = j & (KPC - 1);
        Ahc[j] = (_Float16)((r < NC && c < NC) ? Ac[(size_t)r * NC + c] : 0.f);
        return;
    }
    j -= KPC * KPC;
    if (j < KPP * KPP) {
        int r = j / KPP, c = j - r * KPP;
        Ahp[j] = (_Float16)((r < NP && c < NP) ? Ap[(size_t)r * NP + c] : 0.f);
        return;
    }
    j -= KPP * KPP;
    if (j < 64 * KPC) {
        int c = j >> 11, r = j & (KPC - 1);
        Xtc[j] = (_Float16)((r < NC) ? Xc[(size_t)r * 64 + c] : 0.f);
        return;
    }
    j -= 64 * KPC;
    if (j < 64 * KPP) {
        int c = j / KPP, r = j - c * KPP;
        Xtp[j] = (_Float16)((r < NP) ? Xp[(size_t)r * 64 + c] : 0.f);
        return;
    }
    j -= 64 * KPP;
    if (j < 64 * KPC) { Xtca[j] = (_Float16)0.f; return; }
    j -= 64 * KPC;
    if (j < 64 * KPP) { Xtpa[j] = (_Float16)0.f; }
}
#define PREP_TOTAL (16896 + NW * 80 + 2048000 + 1536000 + 131072 + 8192 + 4096 + 131072 + 8192 + 4096 + 98304 + 65536 + 65536 + 12288 + KPC * KPC + KPP * KPP + 64 * KPC + 64 * KPP + 64 * KPC + 64 * KPP)

// =============== MEGA kernel: GNN-MFMA (blocks 0..NC-1) + CNN (rest) ===============
// GNN: per compound, hs=relu(xs@W+b) then xs+=adj@hs, 3 layers, all on MFMA.
//   xs fp16 [48][72] (rows 40..47 zero), hsT fp16 [64][72] (k 48..63 zero),
//   adj in 6 half8 register fragments (zeros for row/k >= 40; {0,1} exact fp16).
//   Wave w owns output cols [16w,16w+16). Same fragment convention as CNN/MLP.
// CNN: banded-MFMA 3-layer conv, unchanged.
__global__ __launch_bounds__(256) void mega_kernel(
    // CNN
    const int* __restrict__ proteins, const _Float16* __restrict__ ehp,
    const half8_t* __restrict__ wtab, const float* __restrict__ b_cnn,
    float* __restrict__ prot_part,
    // GNN
    const int* __restrict__ compounds, const float* __restrict__ adjacencies,
    const float* __restrict__ embed_fp, const _Float16* __restrict__ wgt,
    const float* __restrict__ b_gnn, _Float16* __restrict__ comp_h)
{
    __shared__ union SM {
        struct { half8_t bufA8[62 * 16]; half8_t bufB8[62 * 16]; } c;   // 31744 B
        struct { _Float16 xs[48 * 72]; _Float16 hsT[64 * 72]; } g;      // 16128 B
    } sm;
    const int bx = blockIdx.x;
    const int tid = threadIdx.x;
    const int lane = tid & 63, wid = tid >> 6;
    const int m = lane & 15, g = lane >> 4;

    if (bx < NC) {
        // ---------------- GNN branch (MFMA) ----------------
        auto& G = sm.g;
        const int n = bx;
        const int colL = wid * 16 + m;

        // stage xs rows 0..39 (fp32 gather -> fp16); zero rows 40..47
        for (int j = tid; j < 48 * 64; j += 256) {
            int r = j >> 6, c = j & 63;
            _Float16 v = (_Float16)0.f;
            if (r < 40) v = (_Float16)embed_fp[(size_t)compounds[n * NA + r] * 64 + c];
            G.xs[r * 72 + c] = v;
        }
        // zero hsT once (k rows 48..63 must stay 0 across layers)
        for (int j = tid; j < 64 * 72 / 8; j += 256) ((half8_t*)G.hsT)[j] = (half8_t){};

        // preload adj A-fragments (row = t*16+m, k = s*32+8g..+7)
        half8_t adjf[3][2];
        #pragma unroll
        for (int t = 0; t < 3; ++t)
            #pragma unroll
            for (int s = 0; s < 2; ++s) {
                half8_t v = {};
                int row = t * 16 + m, k0 = s * 32 + 8 * g;
                if (row < 40 && k0 < 40) {
                    const float* src = &adjacencies[(size_t)n * 1600 + row * 40 + k0];
                    #pragma unroll
                    for (int i = 0; i < 8; ++i) v[i] = (_Float16)src[i];
                }
                adjf[t][s] = v;
            }
        __syncthreads();

        for (int l = 0; l < 3; ++l) {
            // hs = relu(xs@W + b) -> hsT (wave's 16-col slice)
            float bcol = b_gnn[l * 64 + colL];
            #pragma unroll
            for (int t = 0; t < 3; ++t) {
                f32x4 acc = {bcol, bcol, bcol, bcol};
                #pragma unroll
                for (int s = 0; s < 2; ++s) {
                    half8_t a = *(const half8_t*)&G.xs[(t * 16 + m) * 72 + s * 32 + 8 * g];
                    half8_t b = *(const half8_t*)&wgt[(size_t)(l * 64 + colL) * 64 + s * 32 + 8 * g];
                    acc = __builtin_amdgcn_mfma_f32_16x16x32_f16(a, b, acc, 0, 0, 0);
                }
                half4_t h4;
                #pragma unroll
                for (int j = 0; j < 4; ++j) h4[j] = (_Float16)fmaxf(acc[j], 0.f);
                *(half4_t*)&G.hsT[colL * 72 + t * 16 + 4 * g] = h4;
            }
            __syncthreads();
            // xs += adj @ hs   (C-in = old xs; each wave touches only its col slice)
            #pragma unroll
            for (int t = 0; t < 3; ++t) {
                f32x4 acc;
                #pragma unroll
                for (int j = 0; j < 4; ++j)
                    acc[j] = (float)G.xs[(t * 16 + 4 * g + j) * 72 + colL];
                #pragma unroll
                for (int s = 0; s < 2; ++s) {
                    half8_t b = *(const half8_t*)&G.hsT[colL * 72 + s * 32 + 8 * g];
                    acc = __builtin_amdgcn_mfma_f32_16x16x32_f16(adjf[t][s], b, acc, 0, 0, 0);
                }
                #pragma unroll
                for (int j = 0; j < 4; ++j)
                    G.xs[(t * 16 + 4 * g + j) * 72 + colL] = (_Float16)acc[j];
            }
            __syncthreads();
        }
        if (tid < 64) {
            float s = 0.f;
            for (int r = 0; r < 40; ++r) s += (float)G.xs[r * 72 + tid];
            comp_h[n * 64 + tid] = (_Float16)(s * (1.0f / 40.0f));
        }
        return;
    }

    // ---------------- CNN branch ----------------
    _Float16* bufA = (_Float16*)sm.c.bufA8;
    _Float16* bufB = (_Float16*)sm.c.bufB8;
    half8_t* bufA8 = sm.c.bufA8;
    half8_t* bufB8 = sm.c.bufB8;

    const int cb_ = bx - NC;
    const int tile = cb_ & 15, p = cb_ >> 4;
    const int t0 = tile * 32;
    const int c0 = wid * 16;

    half8_t z = {};
    for (int e = tid; e < 62 * 9; e += 256) {
        int i = e / 9, a = 1 + (e - 9 * i);
        int gr = t0 - 15 + i;
        half8_t v = z;
        if (gr >= 0 && gr < LP)
            v = *(const half8_t*)&ehp[(size_t)proteins[p * LP + gr] * 80 + 8 * a];
        *(half8_t*)&bufA[i * 128 + (((a & 8) | ((a ^ i) & 7)) << 3)] = v;
    }
    // zero read-but-never-stored blocks: bufA blk10; bufB blk1, blk9, blk10
    for (int e = tid; e < 62 * 4; e += 256) {
        int i = e >> 2, w = e & 3;
        if (w == 0)      bufA8[i * 16 + (8 | ((10 ^ i) & 7))] = z;
        else if (w == 1) bufB8[i * 16 + ((1 ^ i) & 7)] = z;
        else {
            int blk = 7 + w;
            bufB8[i * 16 + ((blk & 8) | ((blk ^ i) & 7))] = z;
        }
    }

    half8_t wf[11];
    auto load_wf = [&](int L) {
        #pragma unroll
        for (int dr = 0; dr < 11; ++dr) wf[dr] = wtab[L * 11 * 64 + dr * 64 + lane];
    };
    auto conv_tile = [&](const _Float16* src, int r0, float bias) -> f32x4 {
        f32x4 acc = {bias, bias, bias, bias};
        const int B0 = (c0 + 8) >> 3;
        #pragma unroll
        for (int dr = 0; dr < 11; ++dr) {
            int R = r0 - 5 + dr + m;
            int b = B0 + g;
            half8_t a = *(const half8_t*)&src[R * 128 + (((b & 8) | ((b ^ R) & 7)) << 3)];
            acc = __builtin_amdgcn_mfma_f32_16x16x32_f16(a, wf[dr], acc, 0, 0, 0);
        }
        return acc;
    };
    auto store_tile = [&](_Float16* dst, int r0, f32x4 acc) {
        int pc = c0 + 13 + m;
        #pragma unroll
        for (int j = 0; j < 4; ++j) {
            int row = r0 + 4 * g + j;
            int og = t0 - 15 + row;
            float v = fmaxf(acc[j], 0.f);
            dst[swz_off(row, pc)] = (_Float16)((og >= 0 && og < LP) ? v : 0.f);
        }
    };

    load_wf(0);
    __syncthreads();
    {
        float b0 = b_cnn[0];
        const int r0s[4] = {5, 21, 37, 41};
        #pragma unroll
        for (int k = 0; k < 4; ++k) store_tile(bufB, r0s[k], conv_tile(bufA, r0s[k], b0));
    }
    __syncthreads();
    load_wf(1);
    {
        float b1 = b_cnn[1];
        const int r0s[3] = {10, 26, 36};
        #pragma unroll
        for (int k = 0; k < 3; ++k) store_tile(bufA, r0s[k], conv_tile(bufB, r0s[k], b1));
    }
    __syncthreads();
    load_wf(2);
    {
        float b2 = b_cnn[2];
        float cs = 0.f;
        const int r0s[2] = {15, 31};
        #pragma unroll
        for (int k = 0; k < 2; ++k) {
            f32x4 acc = conv_tile(bufA, r0s[k], b2);
            #pragma unroll
            for (int j = 0; j < 4; ++j) cs += fmaxf(acc[j], 0.f);
        }
        cs += __shfl_xor(cs, 16, 64);
        cs += __shfl_xor(cs, 32, 64);
        if (lane < 16)
            prot_part[((size_t)p * 16 + tile) * 64 + c0 + lane] = cs;
    }
}

__global__ void cnn_reduce(const float* __restrict__ prot_part, _Float16* __restrict__ prot_h)
{
    const int p = blockIdx.x, c = threadIdx.x;
    float s = 0.f;
    for (int t = 0; t < 16; ++t) s += prot_part[((size_t)p * 16 + t) * 64 + c];
    prot_h[p * 64 + c] = (_Float16)(s * (1.0f / 512.0f));
}

// ======== GCN: MFMA split-K GEMM part = A@X (drug z=0, protein z=1) ========
__global__ __launch_bounds__(256) void spk_mfma_dual(
    const _Float16* __restrict__ Ah0, const _Float16* __restrict__ Xt0, float* __restrict__ P0, int M0, int Kp0,
    const _Float16* __restrict__ Ah1, const _Float16* __restrict__ Xt1, float* __restrict__ P1, int M1, int Kp1,
    int nx1)
{
    const _Float16* Ah; const _Float16* Xt; float* part; int M, Kp;
    if (blockIdx.z == 0) { Ah = Ah0; Xt = Xt0; part = P0; M = M0; Kp = Kp0; }
    else { if ((int)blockIdx.x >= nx1) return; Ah = Ah1; Xt = Xt1; part = P1; M = M1; Kp = Kp1; }

    const int tid = threadIdx.x, wid = tid >> 6, lane = tid & 63;
    const int m = lane & 15, g = lane >> 4;
    const int row0 = blockIdx.x * 64 + wid * 16;
    const int chunk = Kp >> 3, k0 = blockIdx.y * chunk;
    const _Float16* Apr = Ah + (size_t)(row0 + m) * Kp + 8 * g;
    f32x4 acc[4] = {};
    for (int kb = k0; kb < k0 + chunk; kb += 32) {
        half8_t af = *(const half8_t*)&Apr[kb];
        #pragma unroll
        for (int t = 0; t < 4; ++t) {
            half8_t bf = *(const half8_t*)&Xt[(size_t)(t * 16 + m) * Kp + kb + 8 * g];
            acc[t] = __builtin_amdgcn_mfma_f32_16x16x32_f16(af, bf, acc[t], 0, 0, 0);
        }
    }
    const int s = blockIdx.y;
    #pragma unroll
    for (int t = 0; t < 4; ++t)
        #pragma unroll
        for (int j = 0; j < 4; ++j) {
            int row = row0 + 4 * g + j;
            if (row < M) part[((size_t)s * M + row) * 64 + t * 16 + m] = acc[t][j];
        }
}

// epilogue: sum 8 partials, @W + bias + relu; nullable H / XtN outputs
__global__ __launch_bounds__(256) void gcn_epi_dual(
    const float* __restrict__ P0, int M0, const float* __restrict__ W0, const float* __restrict__ b0,
    _Float16* __restrict__ H0, _Float16* __restrict__ XtN0, int Kp0,
    const float* __restrict__ P1, int M1, const float* __restrict__ W1, const float* __restrict__ b1,
    _Float16* __restrict__ H1, _Float16* __restrict__ XtN1, int Kp1, int nx1)
{
    const float* part; const float* W; const float* bias; _Float16* H; _Float16* XtN; int M, Kp;
    if (blockIdx.z == 0) { part = P0; W = W0; bias = b0; H = H0; XtN = XtN0; M = M0; Kp = Kp0; }
    else { if ((int)blockIdx.x >= nx1) return; part = P1; W = W1; bias = b1; H = H1; XtN = XtN1; M = M1; Kp = Kp1; }

    __shared__ float Ys[64][68];
    __shared__ float Ws[64][64];
    const int rb = blockIdx.x * 64;
    const int tid = threadIdx.x;
    for (int j = tid; j < 4096; j += 256) Ws[j >> 6][j & 63] = W[j];
    for (int j = tid; j < 4096; j += 256) {
        int r = j >> 6, c = j & 63;
        float sum = 0.f;
        if (rb + r < M)
            for (int t = 0; t < 8; ++t) sum += part[((size_t)t * M + rb + r) * 64 + c];
        Ys[r][c] = sum;
    }
    __syncthreads();
    const int tx = tid & 15, ty = tid >> 4;
    float acc[4][4];
    #pragma unroll
    for (int i = 0; i < 4; ++i)
        #pragma unroll
        for (int j = 0; j < 4; ++j) acc[i][j] = bias[tx * 4 + j];
    for (int d = 0; d < 64; ++d) {
        float a0 = Ys[ty * 4 + 0][d], a1 = Ys[ty * 4 + 1][d];
        float a2 = Ys[ty * 4 + 2][d], a3 = Ys[ty * 4 + 3][d];
        float4 w4 = *(const float4*)&Ws[d][tx * 4];
        acc[0][0] += a0 * w4.x; acc[0][1] += a0 * w4.y; acc[0][2] += a0 * w4.z; acc[0][3] += a0 * w4.w;
        acc[1][0] += a1 * w4.x; acc[1][1] += a1 * w4.y; acc[1][2] += a1 * w4.z; acc[1][3] += a1 * w4.w;
        acc[2][0] += a2 * w4.x; acc[2][1] += a2 * w4.y; acc[2][2] += a2 * w4.z; acc[2][3] += a2 * w4.w;
        acc[3][0] += a3 * w4.x; acc[3][1] += a3 * w4.y; acc[3][2] += a3 * w4.z; acc[3][3] += a3 * w4.w;
    }
    #pragma unroll
    for (int i = 0; i < 4; ++i) {
        int row = rb + ty * 4 + i;
        if (row < M) {
            #pragma unroll
            for (int j = 0; j < 4; ++j) {
                int col = tx * 4 + j;
                float v = fmaxf(acc[i][j], 0.f);
                if (H)   H[(size_t)row * 64 + col] = (_Float16)v;
                if (XtN) XtN[(size_t)col * Kp + row] = (_Float16)v;
            }
        }
    }
}

// ======== MFMA MLP GEMM (dual, col-split) ========
template<int NT, bool GATHER>
__global__ __launch_bounds__(256) void mfma_mlp(
    const _Float16* __restrict__ A0, const int* __restrict__ idx0,
    const _Float16* __restrict__ Bt0, const float* __restrict__ bias0, _Float16* __restrict__ C0,
    const _Float16* __restrict__ A1, const int* __restrict__ idx1,
    const _Float16* __restrict__ Bt1, const float* __restrict__ bias1, _Float16* __restrict__ C1,
    int K, int N)
{
    const _Float16* A; const int* idx; const _Float16* Bt; const float* bias; _Float16* C;
    if (blockIdx.z == 0) { A = A0; idx = idx0; Bt = Bt0; bias = bias0; C = C0; }
    else                 { A = A1; idx = idx1; Bt = Bt1; bias = bias1; C = C1; }
    const int tid = threadIdx.x, wid = tid >> 6, lane = tid & 63;
    const int m = lane & 15, g = lane >> 4;
    const int row0 = blockIdx.x * 64 + wid * 16;
    const int col0 = blockIdx.y * (NT * 16);
    size_t arow = GATHER ? (size_t)idx[row0 + m] : (size_t)(row0 + m);
    const _Float16* Ap = A + arow * (size_t)K + 8 * g;
    f32x4 acc[NT] = {};
    for (int kb = 0; kb < K; kb += 32) {
        half8_t af = *(const half8_t*)&Ap[kb];
        #pragma unroll
        for (int t = 0; t < NT; ++t) {
            half8_t bf = *(const half8_t*)&Bt[(size_t)(col0 + t * 16 + m) * K + kb + 8 * g];
            acc[t] = __builtin_amdgcn_mfma_f32_16x16x32_f16(af, bf, acc[t], 0, 0, 0);
        }
    }
    __shared__ float cb[4][16][17];
    const int rr = lane >> 2, c4 = (lane & 3) * 4;
    #pragma unroll
    for (int t = 0; t < NT; ++t) {
        #pragma unroll
        for (int j = 0; j < 4; ++j) cb[wid][4 * g + j][m] = acc[t][j];
        half4_t h;
        #pragma unroll
        for (int j = 0; j < 4; ++j)
            h[j] = (_Float16)fmaxf(cb[wid][rr][c4 + j] + bias[col0 + t * 16 + c4 + j], 0.f);
        *(half4_t*)&C[(size_t)(row0 + rr) * N + col0 + t * 16 + c4] = h;
    }
}

// head GEMM1 with fused concat
__global__ __launch_bounds__(256) void mfma_head1(
    const int* __restrict__ idx_c, const int* __restrict__ idx_p,
    const _Float16* __restrict__ ci, const _Float16* __restrict__ xc, const _Float16* __restrict__ fd,
    const _Float16* __restrict__ pi, const _Float16* __restrict__ xp, const _Float16* __restrict__ fp,
    const _Float16* __restrict__ Bt, const float* __restrict__ bias, _Float16* __restrict__ C)
{
    const int tid = threadIdx.x, wid = tid >> 6, lane = tid & 63;
    const int m = lane & 15, g = lane >> 4;
    const int row0 = blockIdx.x * 64 + wid * 16;
    const int col0 = blockIdx.y * 32;
    int ic = idx_c[row0 + m], ip = idx_p[row0 + m];
    const _Float16* segs[6] = {
        ci + (size_t)ic * 64 + 8 * g,  xc + (size_t)ic * 64 + 8 * g,
        fd + (size_t)(row0 + m) * 64 + 8 * g,
        pi + (size_t)ip * 64 + 8 * g,  xp + (size_t)ip * 64 + 8 * g,
        fp + (size_t)(row0 + m) * 64 + 8 * g };
    f32x4 acc[2] = {};
    #pragma unroll
    for (int kb = 0; kb < 384; kb += 32) {
        half8_t af = *(const half8_t*)&segs[kb / 64][kb & 63];
        #pragma unroll
        for (int t = 0; t < 2; ++t) {
            half8_t bf = *(const half8_t*)&Bt[(size_t)(col0 + t * 16 + m) * 384 + kb + 8 * g];
            acc[t] = __builtin_amdgcn_mfma_f32_16x16x32_f16(af, bf, acc[t], 0, 0, 0);
        }
    }
    __shared__ float cb[4][16][17];
    const int rr = lane >> 2, c4 = (lane & 3) * 4;
    #pragma unroll
    for (int t = 0; t < 2; ++t) {
        #pragma unroll
        for (int j = 0; j < 4; ++j) cb[wid][4 * g + j][m] = acc[t][j];
        half4_t h;
        #pragma unroll
        for (int j = 0; j < 4; ++j)
            h[j] = (_Float16)fmaxf(cb[wid][rr][c4 + j] + bias[col0 + t * 16 + c4 + j], 0.f);
        *(half4_t*)&C[(size_t)(row0 + rr) * 256 + col0 + t * 16 + c4] = h;
    }
}

// head GEMM3 + fused final 256x2 matmul + sigmoid
__global__ __launch_bounds__(256) void mfma_head3(
    const _Float16* __restrict__ A, const _Float16* __restrict__ Bt,
    const float* __restrict__ bias, const float* __restrict__ Wi, const float* __restrict__ bi,
    float* __restrict__ out)
{
    const int tid = threadIdx.x, wid = tid >> 6, lane = tid & 63;
    const int m = lane & 15, g = lane >> 4;
    const int row0 = blockIdx.x * 64 + wid * 16;
    const _Float16* Ap = A + (size_t)(row0 + m) * 256 + 8 * g;
    f32x4 acc[16] = {};
    for (int kb = 0; kb < 256; kb += 32) {
        half8_t af = *(const half8_t*)&Ap[kb];
        #pragma unroll
        for (int t = 0; t < 16; ++t) {
            half8_t bf = *(const half8_t*)&Bt[(size_t)(t * 16 + m) * 256 + kb + 8 * g];
            acc[t] = __builtin_amdgcn_mfma_f32_16x16x32_f16(af, bf, acc[t], 0, 0, 0);
        }
    }
    float p0[4] = {}, p1[4] = {};
    #pragma unroll
    for (int t = 0; t < 16; ++t) {
        float w0 = Wi[(t * 16 + m) * 2], w1 = Wi[(t * 16 + m) * 2 + 1];
        float bc = bias[t * 16 + m];
        #pragma unroll
        for (int j = 0; j < 4; ++j) {
            float v = fmaxf(acc[t][j] + bc, 0.f);
            p0[j] += v * w0; p1[j] += v * w1;
        }
    }
    #pragma unroll
    for (int d = 1; d < 16; d <<= 1) {
        #pragma unroll
        for (int j = 0; j < 4; ++j) {
            p0[j] += __shfl_xor(p0[j], d, 64);
            p1[j] += __shfl_xor(p1[j], d, 64);
        }
    }
    if (m == 0) {
        float B0 = bi[0], B1 = bi[1];
        #pragma unroll
        for (int j = 0; j < 4; ++j) {
            int r = row0 + 4 * g + j;
            out[r * 2 + 0] = 1.f / (1.f + expf(-(p0[j] + B0)));
            out[r * 2 + 1] = 1.f / (1.f + expf(-(p1[j] + B1)));
        }
    }
}

// ======================= launch =======================
extern "C" void kernel_launch(void* const* d_in, const int* in_sizes, int n_in,
                              void* d_out, int out_size, void* d_ws, size_t ws_size,
                              hipStream_t stream)
{
    const int*   idx_c        = (const int*)  d_in[0];
    const int*   idx_p        = (const int*)  d_in[1];
    const int*   compounds    = (const int*)  d_in[2];
    const int*   proteins     = (const int*)  d_in[3];
    const float* adjacencies  = (const float*)d_in[4];
    const float* A_c          = (const float*)d_in[5];
    const float* A_p          = (const float*)d_in[6];
    const float* embed_fp     = (const float*)d_in[7];
    const float* embed_word   = (const float*)d_in[8];
    const float* Xs_c         = (const float*)d_in[9];
    const float* Xs_p         = (const float*)d_in[10];
    const float* drug_feat    = (const float*)d_in[11];
    const float* protein_feat = (const float*)d_in[12];
    const float* W_gnn        = (const float*)d_in[13];
    const float* b_gnn        = (const float*)d_in[14];
    const float* K_cnn        = (const float*)d_in[15];
    const float* b_cnn        = (const float*)d_in[16];
    const float* W_gcn_d      = (const float*)d_in[17];
    const float* b_gcn_d      = (const float*)d_in[18];
    const float* W_gcn_p      = (const float*)d_in[19];
    const float* b_gcn_p      = (const float*)d_in[20];
    const float* Wd1 = (const float*)d_in[21]; const float* bd1 = (const float*)d_in[22];
    const float* Wd2 = (const float*)d_in[23]; const float* bd2 = (const float*)d_in[24];
    const float* Wd3 = (const float*)d_in[25]; const float* bd3 = (const float*)d_in[26];
    const float* Wp1 = (const float*)d_in[27]; const float* bp1 = (const float*)d_in[28];
    const float* Wp2 = (const float*)d_in[29]; const float* bp2 = (const float*)d_in[30];
    const float* Wp3 = (const float*)d_in[31]; const float* bp3 = (const float*)d_in[32];
    const float* Wo1 = (const float*)d_in[33]; const float* bo1 = (const float*)d_in[34];
    const float* Wo2 = (const float*)d_in[35]; const float* bo2 = (const float*)d_in[36];
    const float* Wo3 = (const float*)d_in[37]; const float* bo3 = (const float*)d_in[38];
    const float* W_int = (const float*)d_in[39]; const float* b_int = (const float*)d_in[40];

    float* ws = (float*)d_ws;
    float* prot_part = ws; ws += NP * 16 * 64;
    float* wtab_g    = ws; ws += 8448;
    float* ehp_g     = ws; ws += NW * 40;
    float* part_c    = ws; ws += 8 * NC * 64;
    float* part_p    = ws; ws += 8 * NP * 64;
    _Float16* Ah_c  = (_Float16*)ws; ws += KPC * KPC / 2;
    _Float16* Ah_p  = (_Float16*)ws; ws += KPP * KPP / 2;
    _Float16* Xt_c  = (_Float16*)ws; ws += 32 * KPC;
    _Float16* Xt_p  = (_Float16*)ws; ws += 32 * KPP;
    _Float16* Xt_ca = (_Float16*)ws; ws += 32 * KPC;
    _Float16* Xt_pa = (_Float16*)ws; ws += 32 * KPP;
    _Float16* wgt_g = (_Float16*)ws; ws += 6144;
    _Float16* comp_h  = (_Float16*)ws; ws += NC * 32;
    _Float16* prot_h  = (_Float16*)ws; ws += NP * 32;
    _Float16* Xcb_h   = (_Float16*)ws; ws += NC * 32;
    _Float16* Xpb_h   = (_Float16*)ws; ws += NP * 32;
    _Float16* drug_h  = (_Float16*)ws; ws += NC * 512;
    _Float16* protf_h = (_Float16*)ws; ws += NP * 512;
    _Float16* wd1t = (_Float16*)ws; ws += 65536;
    _Float16* wd2t = (_Float16*)ws; ws += 4096;
    _Float16* wd3t = (_Float16*)ws; ws += 2048;
    _Float16* wp1t = (_Float16*)ws; ws += 65536;
    _Float16* wp2t = (_Float16*)ws; ws += 4096;
    _Float16* wp3t = (_Float16*)ws; ws += 2048;
    _Float16* wo1t = (_Float16*)ws; ws += 49152;
    _Float16* wo2t = (_Float16*)ws; ws += 32768;
    _Float16* wo3t = (_Float16*)ws; ws += 32768;
    _Float16* fd1h = (_Float16*)ws; ws += BSZ * 64;
    _Float16* fd2h = (_Float16*)ws; ws += BSZ * 32;
    _Float16* fd3h = (_Float16*)ws; ws += BSZ * 32;
    _Float16* fp1h = (_Float16*)ws; ws += BSZ * 64;
    _Float16* fp2h = (_Float16*)ws; ws += BSZ * 32;
    _Float16* fp3h = (_Float16*)ws; ws += BSZ * 32;
    _Float16* h1h  = (_Float16*)ws; ws += BSZ * 128;
    _Float16* h2h  = (_Float16*)ws; ws += BSZ * 128;
    (void)ws_size; (void)in_sizes; (void)n_in; (void)out_size;

    // one-time prep (single kernel)
    prep_all<<<(PREP_TOTAL + 255) / 256, 256, 0, stream>>>(
        K_cnn, (_Float16*)wtab_g, embed_word, (_Float16*)ehp_g,
        drug_feat, protein_feat, Wd1, Wd2, Wd3, Wp1, Wp2, Wp3, Wo1, Wo2, Wo3,
        drug_h, protf_h, wd1t, wd2t, wd3t, wp1t, wp2t, wp3t, wo1t, wo2t, wo3t,
        W_gnn, wgt_g,
        A_c, A_p, Xs_c, Xs_p, Ah_c, Ah_p, Xt_c, Xt_p, Xt_ca, Xt_pa);
    // GNN (blocks 0..NC-1) + CNN (blocks NC..NC+16*NP-1) in one dispatch
    mega_kernel<<<NC + 16 * NP, 256, 0, stream>>>(
        proteins, (const _Float16*)ehp_g, (const half8_t*)wtab_g, b_cnn, prot_part,
        compounds, adjacencies, embed_fp, wgt_g, b_gnn, comp_h);
    cnn_reduce<<<NP, 64, 0, stream>>>(prot_part, prot_h);
    // GCN drug+protein (MFMA)
    spk_mfma_dual<<<dim3(32, 8, 2), 256, 0, stream>>>(
        Ah_c, Xt_c, part_c, NC, KPC, Ah_p, Xt_p, part_p, NP, KPP, 24);
    gcn_epi_dual<<<dim3(32, 1, 2), 256, 0, stream>>>(
        part_c, NC, W_gcn_d, b_gcn_d, nullptr, Xt_ca, KPC,
        part_p, NP, W_gcn_p, b_gcn_p, nullptr, Xt_pa, KPP, 24);
    spk_mfma_dual<<<dim3(32, 8, 2), 256, 0, stream>>>(
        Ah_c, Xt_ca, part_c, NC, KPC, Ah_p, Xt_pa, part_p, NP, KPP, 24);
    gcn_epi_dual<<<dim3(32, 1, 2), 256, 0, stream>>>(
        part_c, NC, W_gcn_d + 4096, b_gcn_d + 64, Xcb_h, nullptr, KPC,
        part_p, NP, W_gcn_p + 4096, b_gcn_p + 64, Xpb_h, nullptr, KPP, 24);
    // annotation MLPs (MFMA, dual, col-split)
    mfma_mlp<2, true ><<<dim3(64, 4, 2), 256, 0, stream>>>(
        drug_h, idx_c, wd1t, bd1, fd1h, protf_h, idx_p, wp1t, bp1, fp1h, 1024, 128);
    mfma_mlp<1, false><<<dim3(64, 4, 2), 256, 0, stream>>>(
        fd1h, nullptr, wd2t, bd2, fd2h, fp1h, nullptr, wp2t, bp2, fp2h, 128, 64);
    mfma_mlp<1, false><<<dim3(64, 4, 2), 256, 0, stream>>>(
        fd2h, nullptr, wd3t, bd3, fd3h, fp2h, nullptr, wp3t, bp3, fp3h, 64, 64);
    // head
    mfma_head1<<<dim3(64, 8), 256, 0, stream>>>(idx_c, idx_p, comp_h, Xcb_h, fd3h,
                                                prot_h, Xpb_h, fp3h, wo1t, bo1, h1h);
    mfma_mlp<2, false><<<dim3(64, 8, 1), 256, 0, stream>>>(
        h1h, nullptr, wo2t, bo2, h2h, h1h, nullptr, wo2t, bo2, h2h, 256, 256);
    mfma_head3<<<64, 256, 0, stream>>>(h2h, wo3t, bo3, W_int, b_int, (float*)d_out);
}